// Round 1
// baseline (499.911 us; speedup 1.0000x reference)
//
#include <hip/hip_runtime.h>
#include <math.h>

#define B_ 2
#define N_ 2048
#define H_ 8
#define DH_ 64
#define DM_ 512
#define R_ 16
#define LAM_ 1.0f
#define SCALE_ 0.125f   // 1/sqrt(64)

// ---------------------------------------------------------------------------
// rb[i] = LAM * ||pde_residuals[i,:]||  (the -LAM*rb[i] row-constant term
// cancels in softmax, so we only ever need the per-key term)
// ---------------------------------------------------------------------------
__global__ void rb_kernel(const float* __restrict__ pde, float* __restrict__ rbs) {
    int i = blockIdx.x * blockDim.x + threadIdx.x;
    if (i >= B_ * N_) return;
    const float4* p = (const float4*)(pde + (size_t)i * R_);
    float s = 0.f;
#pragma unroll
    for (int j = 0; j < 4; ++j) {
        float4 v = p[j];
        s += v.x * v.x + v.y * v.y + v.z * v.z + v.w * v.w;
    }
    rbs[i] = LAM_ * sqrtf(s);
}

// ---------------------------------------------------------------------------
// out[M][N] = A[M][K] @ W[N][K]^T + bias[N]   (torch Linear)
// fp32 tiled: BM=BN=64, BK=16, 256 threads, 4x4 per thread
// ---------------------------------------------------------------------------
__global__ __launch_bounds__(256) void gemm_bt(const float* __restrict__ A,
                                               const float* __restrict__ W,
                                               const float* __restrict__ bias,
                                               float* __restrict__ out,
                                               int M, int N, int K) {
    __shared__ float As[16][64];
    __shared__ float Ws[16][64];
    int t = threadIdx.x;
    int m0 = blockIdx.x * 64;
    int n0 = blockIdx.y * 64;
    int tx = t & 15, ty = t >> 4;
    int lrow = t >> 2;        // 0..63
    int lk = (t & 3) * 4;     // 0,4,8,12
    float acc[4][4] = {};

    for (int k0 = 0; k0 < K; k0 += 16) {
        __syncthreads();
        float4 a4 = *(const float4*)(A + (size_t)(m0 + lrow) * K + k0 + lk);
        float4 w4 = *(const float4*)(W + (size_t)(n0 + lrow) * K + k0 + lk);
        As[lk + 0][lrow] = a4.x; As[lk + 1][lrow] = a4.y;
        As[lk + 2][lrow] = a4.z; As[lk + 3][lrow] = a4.w;
        Ws[lk + 0][lrow] = w4.x; Ws[lk + 1][lrow] = w4.y;
        Ws[lk + 2][lrow] = w4.z; Ws[lk + 3][lrow] = w4.w;
        __syncthreads();
#pragma unroll
        for (int kk = 0; kk < 16; ++kk) {
            float4 av = *(const float4*)&As[kk][ty * 4];
            float4 bv = *(const float4*)&Ws[kk][tx * 4];
            float a[4] = {av.x, av.y, av.z, av.w};
            float b[4] = {bv.x, bv.y, bv.z, bv.w};
#pragma unroll
            for (int i = 0; i < 4; ++i)
#pragma unroll
                for (int j = 0; j < 4; ++j)
                    acc[i][j] = fmaf(a[i], b[j], acc[i][j]);
        }
    }
#pragma unroll
    for (int i = 0; i < 4; ++i) {
        int row = m0 + ty * 4 + i;
        float4 o;
        o.x = acc[i][0] + bias[n0 + tx * 4 + 0];
        o.y = acc[i][1] + bias[n0 + tx * 4 + 1];
        o.z = acc[i][2] + bias[n0 + tx * 4 + 2];
        o.w = acc[i][3] + bias[n0 + tx * 4 + 3];
        *(float4*)(out + (size_t)row * N + n0 + tx * 4) = o;
    }
}

// ---------------------------------------------------------------------------
// Flash attention, fp32. Block = 256 threads, QT=32 q-rows, KT=64 keys/tile.
// Thread t: q-row r = t>>3, d-slice / column-group cg = t&7.
// softmax over: q.k*SCALE - LAM*rb[j]  (row term cancels), mask==0 -> -inf
// ---------------------------------------------------------------------------
#define QT 32
#define KT 64

__global__ __launch_bounds__(256) void attn_kernel(
    const float* __restrict__ q, const float* __restrict__ k,
    const float* __restrict__ v, const float* __restrict__ rbs,
    const int* __restrict__ mask, float* __restrict__ out) {
    __shared__ float Ks[KT][68];   // pad 68: j=cg+8*jj reads hit distinct banks
    __shared__ float Vs[KT][64];   // unpadded: 2-way (free) on PV reads
    __shared__ float Ps[QT][68];

    int t = threadIdx.x;
    int qt = blockIdx.x;          // q tile
    int bh = blockIdx.y;          // b*H + h
    int b = bh >> 3, h = bh & 7;
    int m0 = qt * QT;
    int r = t >> 3, cg = t & 7;

    // q row -> registers (broadcast across the 8 lanes of a group; L1-served)
    float qreg[64];
    const float* qrow = q + ((size_t)(b * N_ + m0 + r)) * DM_ + h * DH_;
#pragma unroll
    for (int d4 = 0; d4 < 16; ++d4) {
        float4 v4 = *(const float4*)(qrow + d4 * 4);
        qreg[d4 * 4 + 0] = v4.x; qreg[d4 * 4 + 1] = v4.y;
        qreg[d4 * 4 + 2] = v4.z; qreg[d4 * 4 + 3] = v4.w;
    }

    float Oa[8] = {};
    float mrun = -INFINITY, lrun = 0.f;
    const int* mrow = mask + ((size_t)b * N_ + m0 + r) * N_;

    int srow = t >> 4;            // staging: 0..15
    int scol = (t & 15) * 4;      // 0..60

    for (int k0 = 0; k0 < N_; k0 += KT) {
        __syncthreads();
#pragma unroll
        for (int i = 0; i < 4; ++i) {
            int row = srow + i * 16;
            const float* kr = k + ((size_t)(b * N_ + k0 + row)) * DM_ + h * DH_;
            const float* vr = v + ((size_t)(b * N_ + k0 + row)) * DM_ + h * DH_;
            float4 k4 = *(const float4*)(kr + scol);
            *(float4*)&Vs[row][scol] = *(const float4*)(vr + scol);
            Ks[row][scol + 0] = k4.x; Ks[row][scol + 1] = k4.y;
            Ks[row][scol + 2] = k4.z; Ks[row][scol + 3] = k4.w;
        }
        __syncthreads();

        // ---- S = q.K^T * scale - rb[j], mask, online softmax ----
        float sloc[8];
        float mloc = -INFINITY;
#pragma unroll
        for (int jj = 0; jj < 8; ++jj) {
            int j = cg + jj * 8;
            float s = 0.f;
#pragma unroll
            for (int d4 = 0; d4 < 16; ++d4) {
                float4 k4 = *(const float4*)&Ks[j][d4 * 4];
                s = fmaf(qreg[d4 * 4 + 0], k4.x, s);
                s = fmaf(qreg[d4 * 4 + 1], k4.y, s);
                s = fmaf(qreg[d4 * 4 + 2], k4.z, s);
                s = fmaf(qreg[d4 * 4 + 3], k4.w, s);
            }
            s = s * SCALE_ - rbs[b * N_ + k0 + j];
            if (mrow[k0 + j] == 0) s = -INFINITY;
            sloc[jj] = s;
            mloc = fmaxf(mloc, s);
        }
#pragma unroll
        for (int off = 1; off < 8; off <<= 1)
            mloc = fmaxf(mloc, __shfl_xor(mloc, off, 8));
        float mnew = fmaxf(mrun, mloc);
        float corr = __expf(mrun - mnew);   // first tile: exp(-inf)=0
        float psum = 0.f;
#pragma unroll
        for (int jj = 0; jj < 8; ++jj) {
            float p = __expf(sloc[jj] - mnew);
            Ps[r][cg + jj * 8] = p;
            psum += p;
        }
#pragma unroll
        for (int off = 1; off < 8; off <<= 1)
            psum += __shfl_xor(psum, off, 8);
        lrun = lrun * corr + psum;
        mrun = mnew;
#pragma unroll
        for (int dd = 0; dd < 8; ++dd) Oa[dd] *= corr;
        __syncthreads();   // Ps visible (conservative; also orders Vs reuse)

        // ---- O += P @ V ----
#pragma unroll
        for (int j = 0; j < KT; ++j) {
            float p = Ps[r][j];
            const float* vrow = &Vs[j][cg * 8];
            float4 v0 = *(const float4*)(vrow);
            float4 v1 = *(const float4*)(vrow + 4);
            Oa[0] = fmaf(p, v0.x, Oa[0]); Oa[1] = fmaf(p, v0.y, Oa[1]);
            Oa[2] = fmaf(p, v0.z, Oa[2]); Oa[3] = fmaf(p, v0.w, Oa[3]);
            Oa[4] = fmaf(p, v1.x, Oa[4]); Oa[5] = fmaf(p, v1.y, Oa[5]);
            Oa[6] = fmaf(p, v1.z, Oa[6]); Oa[7] = fmaf(p, v1.w, Oa[7]);
        }
    }

    float inv = 1.f / lrun;
    float* orow = out + ((size_t)(b * N_ + m0 + r)) * DM_ + h * DH_ + cg * 8;
    float4 o0, o1;
    o0.x = Oa[0] * inv; o0.y = Oa[1] * inv; o0.z = Oa[2] * inv; o0.w = Oa[3] * inv;
    o1.x = Oa[4] * inv; o1.y = Oa[5] * inv; o1.z = Oa[6] * inv; o1.w = Oa[7] * inv;
    *(float4*)orow = o0;
    *(float4*)(orow + 4) = o1;
}

// ---------------------------------------------------------------------------
extern "C" void kernel_launch(void* const* d_in, const int* in_sizes, int n_in,
                              void* d_out, int out_size, void* d_ws, size_t ws_size,
                              hipStream_t stream) {
    const float* x   = (const float*)d_in[0];
    const float* pde = (const float*)d_in[1];
    const int*   msk = (const int*)d_in[2];
    const float* Wq  = (const float*)d_in[3];
    const float* bq  = (const float*)d_in[4];
    const float* Wk  = (const float*)d_in[5];
    const float* bk  = (const float*)d_in[6];
    const float* Wv  = (const float*)d_in[7];
    const float* bv  = (const float*)d_in[8];
    const float* Wo  = (const float*)d_in[9];
    const float* bo  = (const float*)d_in[10];
    float* out = (float*)d_out;

    const size_t TOK = (size_t)B_ * N_;      // 4096
    const size_t MAT = TOK * DM_;            // 2M floats
    float* ws  = (float*)d_ws;
    float* qb  = ws;
    float* kb  = ws + MAT;
    float* vb  = ws + 2 * MAT;
    float* ao  = ws + 3 * MAT;
    float* rbs = ws + 4 * MAT;

    rb_kernel<<<(TOK + 255) / 256, 256, 0, stream>>>(pde, rbs);

    dim3 gg(TOK / 64, DM_ / 64);
    gemm_bt<<<gg, 256, 0, stream>>>(x, Wq, bq, qb, TOK, DM_, DM_);
    gemm_bt<<<gg, 256, 0, stream>>>(x, Wk, bk, kb, TOK, DM_, DM_);
    gemm_bt<<<gg, 256, 0, stream>>>(x, Wv, bv, vb, TOK, DM_, DM_);

    dim3 ga(N_ / QT, B_ * H_);
    attn_kernel<<<ga, 256, 0, stream>>>(qb, kb, vb, rbs, msk, ao);

    gemm_bt<<<gg, 256, 0, stream>>>(ao, Wo, bo, out, TOK, DM_, DM_);
}

// Round 2
// 254.596 us; speedup vs baseline: 1.9635x; 1.9635x over previous
//
#include <hip/hip_runtime.h>
#include <math.h>

#define B_ 2
#define N_ 2048
#define H_ 8
#define DH_ 64
#define DM_ 512
#define R_ 16
#define LAM_ 1.0f
#define SCALE_ 0.125f   // 1/sqrt(64)

typedef unsigned short u16;
typedef u16 u16x4 __attribute__((ext_vector_type(4)));
typedef u16 u16x8 __attribute__((ext_vector_type(8)));
typedef __bf16 bf16x8 __attribute__((ext_vector_type(8)));
typedef float f32x4 __attribute__((ext_vector_type(4)));

static __device__ __forceinline__ u16 f2bf(float f) {
    union { float f; unsigned u; } v; v.f = f;
    unsigned r = v.u + 0x7FFF + ((v.u >> 16) & 1);   // RNE
    return (u16)(r >> 16);
}

// ---------------------------------------------------------------------------
// rb[i] = LAM * ||pde_residuals[i,:]||  (row-constant term cancels in softmax)
// ---------------------------------------------------------------------------
__global__ void rb_kernel(const float* __restrict__ pde, float* __restrict__ rbs) {
    int i = blockIdx.x * blockDim.x + threadIdx.x;
    if (i >= B_ * N_) return;
    const float4* p = (const float4*)(pde + (size_t)i * R_);
    float s = 0.f;
#pragma unroll
    for (int j = 0; j < 4; ++j) {
        float4 v = p[j];
        s += v.x * v.x + v.y * v.y + v.z * v.z + v.w * v.w;
    }
    rbs[i] = LAM_ * sqrtf(s);
}

// ---------------------------------------------------------------------------
// per-64x64-tile "has any zero" flag so the attention fast-path can skip the
// per-element mask gather (input mask is all ones -> flags all 0)
// ---------------------------------------------------------------------------
__global__ __launch_bounds__(256) void mask_scan(const int* __restrict__ mask,
                                                 int* __restrict__ flags) {
    int kt = blockIdx.x, qt = blockIdx.y, b = blockIdx.z;
    __shared__ int red;
    if (threadIdx.x == 0) red = 0;
    __syncthreads();
    int any = 0;
    for (int c = threadIdx.x; c < 1024; c += 256) {
        int row = c >> 4, seg = c & 15;
        int4 m4 = *(const int4*)(mask + (size_t)b * N_ * N_ +
                                 (size_t)(qt * 64 + row) * N_ + kt * 64 + seg * 4);
        any |= (m4.x == 0) | (m4.y == 0) | (m4.z == 0) | (m4.w == 0);
    }
    if (__ballot(any)) {
        if ((threadIdx.x & 63) == 0) atomicOr(&red, 1);
    }
    __syncthreads();
    if (threadIdx.x == 0) flags[(b * 32 + qt) * 32 + kt] = red;
}

// ---------------------------------------------------------------------------
// out = A[M][K] @ W[N][K]^T + bias.  MODE 0: f32 out [M][N].
// MODE 1: bf16 out [M][N], scaled.  MODE 2: bf16 out TRANSPOSED per head:
//         vt[(b*8+h)*64 + d][n_in_batch]  (for attention's PV B-operand)
// ---------------------------------------------------------------------------
template <int MODE>
__global__ __launch_bounds__(256) void gemm_bt(const float* __restrict__ A,
                                               const float* __restrict__ W,
                                               const float* __restrict__ bias,
                                               void* __restrict__ outp,
                                               float scale, int M, int Nc, int K) {
    __shared__ float As[16][64];
    __shared__ float Ws[16][64];
    __shared__ u16 T2[64][66];   // MODE 2 transpose bounce
    int t = threadIdx.x;
    int m0 = blockIdx.x * 64;
    int n0 = blockIdx.y * 64;
    int tx = t & 15, ty = t >> 4;
    int lrow = t >> 2;
    int lk = (t & 3) * 4;
    float acc[4][4] = {};

    for (int k0 = 0; k0 < K; k0 += 16) {
        __syncthreads();
        float4 a4 = *(const float4*)(A + (size_t)(m0 + lrow) * K + k0 + lk);
        float4 w4 = *(const float4*)(W + (size_t)(n0 + lrow) * K + k0 + lk);
        As[lk + 0][lrow] = a4.x; As[lk + 1][lrow] = a4.y;
        As[lk + 2][lrow] = a4.z; As[lk + 3][lrow] = a4.w;
        Ws[lk + 0][lrow] = w4.x; Ws[lk + 1][lrow] = w4.y;
        Ws[lk + 2][lrow] = w4.z; Ws[lk + 3][lrow] = w4.w;
        __syncthreads();
#pragma unroll
        for (int kk = 0; kk < 16; ++kk) {
            float4 av = *(const float4*)&As[kk][ty * 4];
            float4 bv = *(const float4*)&Ws[kk][tx * 4];
            float a[4] = {av.x, av.y, av.z, av.w};
            float b[4] = {bv.x, bv.y, bv.z, bv.w};
#pragma unroll
            for (int i = 0; i < 4; ++i)
#pragma unroll
                for (int j = 0; j < 4; ++j)
                    acc[i][j] = fmaf(a[i], b[j], acc[i][j]);
        }
    }

    if (MODE == 0) {
        float* out = (float*)outp;
#pragma unroll
        for (int i = 0; i < 4; ++i) {
            int row = m0 + ty * 4 + i;
            float4 o;
            o.x = acc[i][0] + bias[n0 + tx * 4 + 0];
            o.y = acc[i][1] + bias[n0 + tx * 4 + 1];
            o.z = acc[i][2] + bias[n0 + tx * 4 + 2];
            o.w = acc[i][3] + bias[n0 + tx * 4 + 3];
            *(float4*)(out + (size_t)row * Nc + n0 + tx * 4) = o;
        }
    } else if (MODE == 1) {
        u16* out = (u16*)outp;
#pragma unroll
        for (int i = 0; i < 4; ++i) {
            int row = m0 + ty * 4 + i;
            u16x4 o;
#pragma unroll
            for (int j = 0; j < 4; ++j)
                o[j] = f2bf((acc[i][j] + bias[n0 + tx * 4 + j]) * scale);
            *(u16x4*)(out + (size_t)row * Nc + n0 + tx * 4) = o;
        }
    } else {   // MODE 2: transposed bf16 per head
        u16* out = (u16*)outp;
#pragma unroll
        for (int i = 0; i < 4; ++i)
#pragma unroll
            for (int j = 0; j < 4; ++j)
                T2[tx * 4 + j][ty * 4 + i] =
                    f2bf((acc[i][j] + bias[n0 + tx * 4 + j]) * scale);
        __syncthreads();
        int bb = m0 >> 11;            // batch (N_=2048 rows per batch)
        int nb = m0 & (N_ - 1);       // n within batch
        int h  = n0 >> 6;             // head (DH_=64)
#pragma unroll
        for (int cc = 0; cc < 2; ++cc) {
            int c = t + cc * 256;
            int d = c >> 3, seg = c & 7;
            u16x8 ov;
#pragma unroll
            for (int jj = 0; jj < 8; ++jj) ov[jj] = T2[d][seg * 8 + jj];
            *(u16x8*)(out + ((size_t)((bb * 8 + h) * 64 + d)) * N_ + nb + seg * 8) = ov;
        }
    }
}

// ---------------------------------------------------------------------------
// MFMA flash attention. 4 waves x 16 q-rows (QBLK=64), KT=64, DH=64.
// S = (q*SCALE).k - rb[j]; mask fast-path via tile flags.
// LDS rows XOR-swizzled (byte ^= (row&7)<<4) -> conflict-free ds_read_b128.
// ---------------------------------------------------------------------------
__global__ __launch_bounds__(256) void attn_mfma(
    const u16* __restrict__ qb, const u16* __restrict__ kb,
    const u16* __restrict__ vtb, const float* __restrict__ rbs,
    const int* __restrict__ mask, const int* __restrict__ flags,
    float* __restrict__ ao) {
    __shared__ char KsB[8192];   // K tile [64 key][64 d] bf16, swizzled
    __shared__ char VtB[8192];   // V^T tile [64 d][64 key] bf16, swizzled
    __shared__ char PsB[8192];   // P per wave [16 q][64 key] bf16, swizzled

    int t = threadIdx.x, l = t & 63, w = t >> 6;
    int qt = blockIdx.x, bh = blockIdx.y;
    int b = bh >> 3, h = bh & 7;
    int m0 = qt * 64;
    int lg = l >> 4, li = l & 15;

    // Q fragments (A-operand): lane holds Q[row=li][d = s*32 + lg*8 + j]
    bf16x8 qa[2];
    {
        const u16* qrow = qb + (size_t)(b * N_ + m0 + w * 16 + li) * DM_ + h * DH_;
        qa[0] = __builtin_bit_cast(bf16x8, *(const u16x8*)(qrow + lg * 8));
        qa[1] = __builtin_bit_cast(bf16x8, *(const u16x8*)(qrow + 32 + lg * 8));
    }

    f32x4 o[4];
#pragma unroll
    for (int dt = 0; dt < 4; ++dt) o[dt] = (f32x4){0.f, 0.f, 0.f, 0.f};
    float mrun[4], lrun[4];
#pragma unroll
    for (int r = 0; r < 4; ++r) { mrun[r] = -INFINITY; lrun[r] = 0.f; }

    for (int k0 = 0; k0 < N_; k0 += 64) {
        int flag = flags[(b * 32 + qt) * 32 + (k0 >> 6)];
        __syncthreads();
#pragma unroll
        for (int cc = 0; cc < 2; ++cc) {
            int c = t + cc * 256;
            int row = c >> 3, seg = c & 7;
            u16x8 kv = *(const u16x8*)(kb + (size_t)(b * N_ + k0 + row) * DM_ +
                                       h * DH_ + seg * 8);
            *(u16x8*)(KsB + ((row * 128 + seg * 16) ^ ((row & 7) << 4))) = kv;
            u16x8 vv = *(const u16x8*)(vtb + ((size_t)bh * DH_ + row) * N_ +
                                       k0 + seg * 8);
            *(u16x8*)(VtB + ((row * 128 + seg * 16) ^ ((row & 7) << 4))) = vv;
        }
        __syncthreads();

        // ---- S = Q.K^T (4 key-tiles of 16) ----
        f32x4 st[4];
#pragma unroll
        for (int kt = 0; kt < 4; ++kt) {
            st[kt] = (f32x4){0.f, 0.f, 0.f, 0.f};
#pragma unroll
            for (int s = 0; s < 2; ++s) {
                int key = kt * 16 + li;
                bf16x8 kf = __builtin_bit_cast(
                    bf16x8, *(const u16x8*)(KsB + ((key * 128 + s * 64 + lg * 16) ^
                                                   ((key & 7) << 4))));
                st[kt] = __builtin_amdgcn_mfma_f32_16x16x32_bf16(qa[s], kf, st[kt],
                                                                 0, 0, 0);
            }
        }

        // ---- bias + (rare) mask ----
        float rbv[4];
#pragma unroll
        for (int kt = 0; kt < 4; ++kt)
            rbv[kt] = rbs[b * N_ + k0 + kt * 16 + li];
#pragma unroll
        for (int kt = 0; kt < 4; ++kt)
#pragma unroll
            for (int r = 0; r < 4; ++r) st[kt][r] -= rbv[kt];
        if (flag) {
#pragma unroll
            for (int kt = 0; kt < 4; ++kt)
#pragma unroll
                for (int r = 0; r < 4; ++r) {
                    int rowg = m0 + w * 16 + lg * 4 + r;
                    int keyg = k0 + kt * 16 + li;
                    if (mask[(size_t)b * N_ * N_ + (size_t)rowg * N_ + keyg] == 0)
                        st[kt][r] = -INFINITY;
                }
        }

        // ---- online softmax (rows live in 16-lane groups) ----
        float mloc[4];
#pragma unroll
        for (int r = 0; r < 4; ++r)
            mloc[r] = fmaxf(fmaxf(st[0][r], st[1][r]), fmaxf(st[2][r], st[3][r]));
#pragma unroll
        for (int off = 1; off < 16; off <<= 1)
#pragma unroll
            for (int r = 0; r < 4; ++r)
                mloc[r] = fmaxf(mloc[r], __shfl_xor(mloc[r], off, 16));

        float corr[4], psum[4];
#pragma unroll
        for (int r = 0; r < 4; ++r) {
            float mnew = fmaxf(fmaxf(mrun[r], mloc[r]), -3.0e38f);
            corr[r] = __expf(mrun[r] - mnew);
            mrun[r] = mnew;
            psum[r] = 0.f;
        }
#pragma unroll
        for (int kt = 0; kt < 4; ++kt)
#pragma unroll
            for (int r = 0; r < 4; ++r) {
                float p = __expf(st[kt][r] - mrun[r]);
                psum[r] += p;
                int prow = lg * 4 + r, key = kt * 16 + li;
                *(u16*)(PsB + w * 2048 +
                        ((prow * 128 + key * 2) ^ ((prow & 7) << 4))) = f2bf(p);
            }
#pragma unroll
        for (int off = 1; off < 16; off <<= 1)
#pragma unroll
            for (int r = 0; r < 4; ++r) psum[r] += __shfl_xor(psum[r], off, 16);
#pragma unroll
        for (int r = 0; r < 4; ++r) lrun[r] = lrun[r] * corr[r] + psum[r];
#pragma unroll
        for (int dt = 0; dt < 4; ++dt)
#pragma unroll
            for (int r = 0; r < 4; ++r) o[dt][r] *= corr[r];

        // ---- O += P @ V ----
        bf16x8 pf[2];
#pragma unroll
        for (int s = 0; s < 2; ++s)
            pf[s] = __builtin_bit_cast(
                bf16x8, *(const u16x8*)(PsB + w * 2048 +
                                        ((li * 128 + s * 64 + lg * 16) ^
                                         ((li & 7) << 4))));
#pragma unroll
        for (int dt = 0; dt < 4; ++dt)
#pragma unroll
            for (int s = 0; s < 2; ++s) {
                int d = dt * 16 + li;
                bf16x8 vf = __builtin_bit_cast(
                    bf16x8, *(const u16x8*)(VtB + ((d * 128 + s * 64 + lg * 16) ^
                                                   ((d & 7) << 4))));
                o[dt] = __builtin_amdgcn_mfma_f32_16x16x32_bf16(pf[s], vf, o[dt],
                                                                0, 0, 0);
            }
    }

    float inv[4];
#pragma unroll
    for (int r = 0; r < 4; ++r) inv[r] = 1.f / lrun[r];
#pragma unroll
    for (int dt = 0; dt < 4; ++dt)
#pragma unroll
        for (int r = 0; r < 4; ++r)
            ao[(size_t)(b * N_ + m0 + w * 16 + lg * 4 + r) * DM_ + h * DH_ +
               dt * 16 + li] = o[dt][r] * inv[r];
}

// ---------------------------------------------------------------------------
extern "C" void kernel_launch(void* const* d_in, const int* in_sizes, int n_in,
                              void* d_out, int out_size, void* d_ws, size_t ws_size,
                              hipStream_t stream) {
    const float* x   = (const float*)d_in[0];
    const float* pde = (const float*)d_in[1];
    const int*   msk = (const int*)d_in[2];
    const float* Wq  = (const float*)d_in[3];
    const float* bq  = (const float*)d_in[4];
    const float* Wk  = (const float*)d_in[5];
    const float* bk  = (const float*)d_in[6];
    const float* Wv  = (const float*)d_in[7];
    const float* bv  = (const float*)d_in[8];
    const float* Wo  = (const float*)d_in[9];
    const float* bo  = (const float*)d_in[10];
    float* out = (float*)d_out;

    const size_t TOK = (size_t)B_ * N_;      // 4096
    const size_t MAT = TOK * DM_;            // 2M elements
    u16* q_bf  = (u16*)d_ws;
    u16* k_bf  = q_bf + MAT;
    u16* vt    = k_bf + MAT;
    float* ao  = (float*)(vt + MAT);
    float* rbs = ao + MAT;
    int* flags = (int*)(rbs + TOK);

    rb_kernel<<<(TOK + 255) / 256, 256, 0, stream>>>(pde, rbs);
    mask_scan<<<dim3(32, 32, 2), 256, 0, stream>>>(msk, flags);

    dim3 gg(TOK / 64, DM_ / 64);
    gemm_bt<1><<<gg, 256, 0, stream>>>(x, Wq, bq, q_bf, SCALE_, TOK, DM_, DM_);
    gemm_bt<1><<<gg, 256, 0, stream>>>(x, Wk, bk, k_bf, 1.0f, TOK, DM_, DM_);
    gemm_bt<2><<<gg, 256, 0, stream>>>(x, Wv, bv, vt,   1.0f, TOK, DM_, DM_);

    dim3 ga(N_ / 64, B_ * H_);
    attn_mfma<<<ga, 256, 0, stream>>>(q_bf, k_bf, vt, rbs, msk, flags, ao);

    gemm_bt<0><<<gg, 256, 0, stream>>>(ao, Wo, bo, out, 1.0f, TOK, DM_, DM_);
}

// Round 3
// 163.014 us; speedup vs baseline: 3.0667x; 1.5618x over previous
//
#include <hip/hip_runtime.h>
#include <math.h>

#define B_ 2
#define N_ 2048
#define H_ 8
#define DH_ 64
#define DM_ 512
#define R_ 16
#define LAM_ 1.0f
#define SCALE_ 0.125f   // 1/sqrt(64)

typedef unsigned short u16;
typedef u16 u16x4 __attribute__((ext_vector_type(4)));
typedef u16 u16x8 __attribute__((ext_vector_type(8)));
typedef __bf16 bf16x8 __attribute__((ext_vector_type(8)));
typedef float f32x4 __attribute__((ext_vector_type(4)));

static __device__ __forceinline__ u16 f2bf(float f) {
    union { float f; unsigned u; } v; v.f = f;
    unsigned r = v.u + 0x7FFF + ((v.u >> 16) & 1);   // RNE
    return (u16)(r >> 16);
}

static __device__ __forceinline__ void gl_lds16(const void* g, void* l) {
    __builtin_amdgcn_global_load_lds(
        (const __attribute__((address_space(1))) unsigned*)g,
        (__attribute__((address_space(3))) unsigned*)l, 16, 0, 0);
}

// ---------------------------------------------------------------------------
// bf16 casts: y=0 -> x (2M), y=1..4 -> Wq,Wk,Wv,Wo (256K each)
// ---------------------------------------------------------------------------
__global__ __launch_bounds__(256) void cast_all(
    const float* __restrict__ x, const float* __restrict__ wq,
    const float* __restrict__ wk, const float* __restrict__ wv,
    const float* __restrict__ wo, u16* __restrict__ xb, u16* __restrict__ wqb,
    u16* __restrict__ wkb, u16* __restrict__ wvb, u16* __restrict__ wob) {
    int y = blockIdx.y;
    const float* src; u16* dst; int n;
    switch (y) {
        case 0: src = x;  dst = xb;  n = 2097152; break;
        case 1: src = wq; dst = wqb; n = 262144;  break;
        case 2: src = wk; dst = wkb; n = 262144;  break;
        case 3: src = wv; dst = wvb; n = 262144;  break;
        default: src = wo; dst = wob; n = 262144; break;
    }
    int i = (blockIdx.x * 256 + threadIdx.x) * 8;
    if (i >= n) return;
    float4 a = *(const float4*)(src + i);
    float4 b = *(const float4*)(src + i + 4);
    u16x8 o;
    o[0] = f2bf(a.x); o[1] = f2bf(a.y); o[2] = f2bf(a.z); o[3] = f2bf(a.w);
    o[4] = f2bf(b.x); o[5] = f2bf(b.y); o[6] = f2bf(b.z); o[7] = f2bf(b.w);
    *(u16x8*)(dst + i) = o;
}

// ---------------------------------------------------------------------------
__global__ void rb_kernel(const float* __restrict__ pde, float* __restrict__ rbs) {
    int i = blockIdx.x * blockDim.x + threadIdx.x;
    if (i >= B_ * N_) return;
    const float4* p = (const float4*)(pde + (size_t)i * R_);
    float s = 0.f;
#pragma unroll
    for (int j = 0; j < 4; ++j) {
        float4 v = p[j];
        s += v.x * v.x + v.y * v.y + v.z * v.z + v.w * v.w;
    }
    rbs[i] = LAM_ * sqrtf(s);
}

// ---------------------------------------------------------------------------
__global__ __launch_bounds__(256) void mask_scan(const int* __restrict__ mask,
                                                 int* __restrict__ flags) {
    int kt = blockIdx.x, qt = blockIdx.y, b = blockIdx.z;
    __shared__ int red;
    if (threadIdx.x == 0) red = 0;
    __syncthreads();
    int any = 0;
    for (int c = threadIdx.x; c < 1024; c += 256) {
        int row = c >> 4, seg = c & 15;
        int4 m4 = *(const int4*)(mask + (size_t)b * N_ * N_ +
                                 (size_t)(qt * 64 + row) * N_ + kt * 64 + seg * 4);
        any |= (m4.x == 0) | (m4.y == 0) | (m4.z == 0) | (m4.w == 0);
    }
    if (__ballot(any)) {
        if ((threadIdx.x & 63) == 0) atomicOr(&red, 1);
    }
    __syncthreads();
    if (threadIdx.x == 0) flags[(b * 32 + qt) * 32 + kt] = red;
}

// ---------------------------------------------------------------------------
// bf16 MFMA GEMM core: out[m0+.. (64)][nn0+.. (64)] = A @ W^T
// A [M][512] bf16, W [512][512] bf16 row-major (rows are output cols).
// BK=64, 256 threads = 4 waves, each 32x32 (2x2 of 16x16 frags).
// LDS linear + pre-swizzled global source, swizzled ds_read (T2, rule #21).
// ---------------------------------------------------------------------------
struct Acc { f32x4 v[2][2]; };

static __device__ __forceinline__ Acc gemm_core(const u16* __restrict__ A,
                                                const u16* __restrict__ W,
                                                int m0, int nn0, char* LDSB) {
    int t = threadIdx.x, l = t & 63, w = t >> 6;
    int lg = l >> 4, li = l & 15;
    int wr = w >> 1, wc = w & 1;
    Acc acc;
#pragma unroll
    for (int m = 0; m < 2; ++m)
#pragma unroll
        for (int n = 0; n < 2; ++n) acc.v[m][n] = (f32x4){0.f, 0.f, 0.f, 0.f};

    int srow_l = l >> 3;                 // 0..7 within chunk
    int colb = ((l & 7) * 16) ^ (srow_l << 4);   // pre-swizzled source col (bytes)

    for (int k0 = 0; k0 < DM_; k0 += 64) {
        __syncthreads();
#pragma unroll
        for (int i = 0; i < 2; ++i) {
            int c = w * 2 + i;
            int row = c * 8 + srow_l;
            gl_lds16(A + (size_t)(m0 + row) * DM_ + k0 + (colb >> 1),
                     LDSB + c * 1024);
            gl_lds16(W + (size_t)(nn0 + row) * DM_ + k0 + (colb >> 1),
                     LDSB + 8192 + c * 1024);
        }
        __syncthreads();
#pragma unroll
        for (int kk = 0; kk < 2; ++kk) {
            bf16x8 af[2], bfr[2];
#pragma unroll
            for (int m = 0; m < 2; ++m) {
                int r = wr * 32 + m * 16 + li;
                af[m] = *(const bf16x8*)(LDSB + r * 128 +
                                         ((kk * 64 + lg * 16) ^ ((r & 7) << 4)));
            }
#pragma unroll
            for (int n = 0; n < 2; ++n) {
                int r = wc * 32 + n * 16 + li;
                bfr[n] = *(const bf16x8*)(LDSB + 8192 + r * 128 +
                                          ((kk * 64 + lg * 16) ^ ((r & 7) << 4)));
            }
#pragma unroll
            for (int m = 0; m < 2; ++m)
#pragma unroll
                for (int n = 0; n < 2; ++n)
                    acc.v[m][n] = __builtin_amdgcn_mfma_f32_16x16x32_bf16(
                        af[m], bfr[n], acc.v[m][n], 0, 0, 0);
        }
    }
    return acc;
}

// ---------------------------------------------------------------------------
// Fused QKV GEMM. grid (64 m-tiles, 24 n-tiles): y>>3 = 0:Q 1:K 2:V
// Q: bf16 [tok][dm] scaled by 1/8.  K: bf16 [tok][dm].  V: bf16 V^T
// vt[(b*8+h)*64+d][tok_in_batch] (transpose free from C-frag layout).
// ---------------------------------------------------------------------------
__global__ __launch_bounds__(256) void gemm_qkv(
    const u16* __restrict__ xb, const u16* __restrict__ wqb,
    const u16* __restrict__ wkb, const u16* __restrict__ wvb,
    const float* __restrict__ bq, const float* __restrict__ bk,
    const float* __restrict__ bv, u16* __restrict__ q_bf,
    u16* __restrict__ k_bf, u16* __restrict__ vt) {
    __shared__ char LDSB[24576];
    int y = blockIdx.y;
    int which = y >> 3;
    int nn0 = (y & 7) * 64;
    const u16* W = which == 0 ? wqb : which == 1 ? wkb : wvb;
    const float* bias = which == 0 ? bq : which == 1 ? bk : bv;
    int m0 = blockIdx.x * 64;
    Acc acc = gemm_core(xb, W, m0, nn0, LDSB);

    int t = threadIdx.x, l = t & 63, w = t >> 6;
    int lg = l >> 4, li = l & 15;
    int wr = w >> 1, wc = w & 1;
    float scale = which == 0 ? SCALE_ : 1.0f;
#pragma unroll
    for (int n = 0; n < 2; ++n) {
        int col = nn0 + wc * 32 + n * 16 + li;
        float bv_ = bias[col];
        if (which < 2) {
            u16* dst = which == 0 ? q_bf : k_bf;
#pragma unroll
            for (int m = 0; m < 2; ++m)
#pragma unroll
                for (int r = 0; r < 4; ++r) {
                    int row = m0 + wr * 32 + m * 16 + lg * 4 + r;
                    dst[(size_t)row * DM_ + col] =
                        f2bf((acc.v[m][n][r] + bv_) * scale);
                }
        } else {
            int h = col >> 6, d = col & 63;
#pragma unroll
            for (int m = 0; m < 2; ++m) {
                int row = m0 + wr * 32 + m * 16 + lg * 4;   // 4 consecutive toks
                int b = row >> 11, nb = row & (N_ - 1);
                u16x4 o;
#pragma unroll
                for (int r = 0; r < 4; ++r) o[r] = f2bf(acc.v[m][n][r] + bv_);
                *(u16x4*)(vt + ((size_t)((b * 8 + h) * 64 + d)) * N_ + nb) = o;
            }
        }
    }
}

// ---------------------------------------------------------------------------
// Output GEMM: out f32 [4096][512] = ao_bf @ Wo^T + bo
// ---------------------------------------------------------------------------
__global__ __launch_bounds__(256) void gemm_out(
    const u16* __restrict__ aob, const u16* __restrict__ wob,
    const float* __restrict__ bo, float* __restrict__ out) {
    __shared__ char LDSB[24576];
    int nn0 = blockIdx.y * 64;
    int m0 = blockIdx.x * 64;
    Acc acc = gemm_core(aob, wob, m0, nn0, LDSB);

    int t = threadIdx.x, l = t & 63, w = t >> 6;
    int lg = l >> 4, li = l & 15;
    int wr = w >> 1, wc = w & 1;
#pragma unroll
    for (int n = 0; n < 2; ++n) {
        int col = nn0 + wc * 32 + n * 16 + li;
        float bv_ = bo[col];
#pragma unroll
        for (int m = 0; m < 2; ++m)
#pragma unroll
            for (int r = 0; r < 4; ++r) {
                int row = m0 + wr * 32 + m * 16 + lg * 4 + r;
                out[(size_t)row * DM_ + col] = acc.v[m][n][r] + bv_;
            }
    }
}

// ---------------------------------------------------------------------------
// Barrier-free MFMA flash attention. 1 wave / block, 16 q-rows.
// K/V fragments loaded DIRECTLY from global (L2-resident; no LDS staging,
// no __syncthreads). P round-trips through wave-private LDS (swizzled).
// Grid 2048 (XCD-swizzled: each XCD keeps 2 heads' K/V hot in its L2).
// ---------------------------------------------------------------------------
__global__ __launch_bounds__(64) void attn2(
    const u16* __restrict__ qb, const u16* __restrict__ kb,
    const u16* __restrict__ vtb, const float* __restrict__ rbs,
    const int* __restrict__ mask, const int* __restrict__ flags,
    u16* __restrict__ aob) {
    __shared__ char PsB[2048];
    int l = threadIdx.x;
    int raw = blockIdx.x;
    int sid = (raw & 7) * 256 + (raw >> 3);   // XCD-contiguous remap (2048 % 8 == 0)
    int qt = sid & 127, bh = sid >> 7;
    int b = bh >> 3, h = bh & 7;
    int m0 = qt * 16;
    int lg = l >> 4, li = l & 15;

    bf16x8 qa[2];
    {
        const u16* qrow = qb + (size_t)(b * N_ + m0 + li) * DM_ + h * DH_;
        qa[0] = __builtin_bit_cast(bf16x8, *(const u16x8*)(qrow + lg * 8));
        qa[1] = __builtin_bit_cast(bf16x8, *(const u16x8*)(qrow + 32 + lg * 8));
    }

    f32x4 o[4];
#pragma unroll
    for (int dt = 0; dt < 4; ++dt) o[dt] = (f32x4){0.f, 0.f, 0.f, 0.f};
    float mrun[4], lrun[4];
#pragma unroll
    for (int r = 0; r < 4; ++r) { mrun[r] = -INFINITY; lrun[r] = 0.f; }

    for (int k0 = 0; k0 < N_; k0 += 64) {
        int flag = flags[(b * 32 + (m0 >> 6)) * 32 + (k0 >> 6)];

        // ---- K fragments direct from global ----
        u16x8 kf[4][2];
#pragma unroll
        for (int kt = 0; kt < 4; ++kt)
#pragma unroll
            for (int s = 0; s < 2; ++s)
                kf[kt][s] = *(const u16x8*)(kb +
                    (size_t)(b * N_ + k0 + kt * 16 + li) * DM_ + h * DH_ +
                    s * 32 + lg * 8);

        f32x4 st[4];
#pragma unroll
        for (int kt = 0; kt < 4; ++kt) {
            st[kt] = (f32x4){0.f, 0.f, 0.f, 0.f};
#pragma unroll
            for (int s = 0; s < 2; ++s)
                st[kt] = __builtin_amdgcn_mfma_f32_16x16x32_bf16(
                    qa[s], __builtin_bit_cast(bf16x8, kf[kt][s]), st[kt], 0, 0, 0);
        }

        // ---- bias + (rare) mask ----
#pragma unroll
        for (int kt = 0; kt < 4; ++kt) {
            float rbv = rbs[b * N_ + k0 + kt * 16 + li];
#pragma unroll
            for (int r = 0; r < 4; ++r) st[kt][r] -= rbv;
        }
        if (flag) {
#pragma unroll
            for (int kt = 0; kt < 4; ++kt)
#pragma unroll
                for (int r = 0; r < 4; ++r) {
                    int rowg = m0 + lg * 4 + r;
                    int keyg = k0 + kt * 16 + li;
                    if (mask[(size_t)b * N_ * N_ + (size_t)rowg * N_ + keyg] == 0)
                        st[kt][r] = -INFINITY;
                }
        }

        // ---- online softmax (row = lg*4+r, reduce over kt + 16 lanes) ----
        float mloc[4];
#pragma unroll
        for (int r = 0; r < 4; ++r)
            mloc[r] = fmaxf(fmaxf(st[0][r], st[1][r]), fmaxf(st[2][r], st[3][r]));
#pragma unroll
        for (int off = 1; off < 16; off <<= 1)
#pragma unroll
            for (int r = 0; r < 4; ++r)
                mloc[r] = fmaxf(mloc[r], __shfl_xor(mloc[r], off, 16));

        float corr[4], psum[4];
#pragma unroll
        for (int r = 0; r < 4; ++r) {
            float mnew = fmaxf(fmaxf(mrun[r], mloc[r]), -3.0e38f);
            corr[r] = __expf(mrun[r] - mnew);
            mrun[r] = mnew;
            psum[r] = 0.f;
        }
#pragma unroll
        for (int kt = 0; kt < 4; ++kt)
#pragma unroll
            for (int r = 0; r < 4; ++r) {
                float p = __expf(st[kt][r] - mrun[r]);
                psum[r] += p;
                int prow = lg * 4 + r, key = kt * 16 + li;
                *(u16*)(PsB + ((prow * 128 + key * 2) ^ ((prow & 7) << 4))) = f2bf(p);
            }
#pragma unroll
        for (int off = 1; off < 16; off <<= 1)
#pragma unroll
            for (int r = 0; r < 4; ++r) psum[r] += __shfl_xor(psum[r], off, 16);
#pragma unroll
        for (int r = 0; r < 4; ++r) lrun[r] = lrun[r] * corr[r] + psum[r];
#pragma unroll
        for (int dt = 0; dt < 4; ++dt)
#pragma unroll
            for (int r = 0; r < 4; ++r) o[dt][r] *= corr[r];

        // ---- O += P @ V (V^T fragments direct from global) ----
        bf16x8 pf[2];
#pragma unroll
        for (int s = 0; s < 2; ++s)
            pf[s] = __builtin_bit_cast(
                bf16x8, *(const u16x8*)(PsB + ((li * 128 + s * 64 + lg * 16) ^
                                               ((li & 7) << 4))));
#pragma unroll
        for (int dt = 0; dt < 4; ++dt)
#pragma unroll
            for (int s = 0; s < 2; ++s) {
                u16x8 vf = *(const u16x8*)(vtb +
                    ((size_t)(bh * DH_ + dt * 16 + li)) * N_ + k0 + s * 32 + lg * 8);
                o[dt] = __builtin_amdgcn_mfma_f32_16x16x32_bf16(
                    pf[s], __builtin_bit_cast(bf16x8, vf), o[dt], 0, 0, 0);
            }
    }

    float inv[4];
#pragma unroll
    for (int r = 0; r < 4; ++r) inv[r] = 1.f / lrun[r];
#pragma unroll
    for (int dt = 0; dt < 4; ++dt)
#pragma unroll
        for (int r = 0; r < 4; ++r)
            aob[(size_t)(b * N_ + m0 + lg * 4 + r) * DM_ + h * DH_ + dt * 16 + li] =
                f2bf(o[dt][r] * inv[r]);
}

// ---------------------------------------------------------------------------
extern "C" void kernel_launch(void* const* d_in, const int* in_sizes, int n_in,
                              void* d_out, int out_size, void* d_ws, size_t ws_size,
                              hipStream_t stream) {
    const float* x   = (const float*)d_in[0];
    const float* pde = (const float*)d_in[1];
    const int*   msk = (const int*)d_in[2];
    const float* Wq  = (const float*)d_in[3];
    const float* bq  = (const float*)d_in[4];
    const float* Wk  = (const float*)d_in[5];
    const float* bk  = (const float*)d_in[6];
    const float* Wv  = (const float*)d_in[7];
    const float* bv  = (const float*)d_in[8];
    const float* Wo  = (const float*)d_in[9];
    const float* bo  = (const float*)d_in[10];
    float* out = (float*)d_out;

    const size_t MAT = (size_t)B_ * N_ * DM_;   // 2M elements
    const size_t WSZ = (size_t)DM_ * DM_;       // 256K
    u16* xb   = (u16*)d_ws;
    u16* q_bf = xb + MAT;
    u16* k_bf = q_bf + MAT;
    u16* vt   = k_bf + MAT;
    u16* aob  = vt + MAT;
    u16* wqb  = aob + MAT;
    u16* wkb  = wqb + WSZ;
    u16* wvb  = wkb + WSZ;
    u16* wob  = wvb + WSZ;
    float* rbs = (float*)(wob + WSZ);
    int* flags = (int*)(rbs + B_ * N_);

    cast_all<<<dim3(1024, 5), 256, 0, stream>>>(x, Wq, Wk, Wv, Wo,
                                                xb, wqb, wkb, wvb, wob);
    rb_kernel<<<(B_ * N_ + 255) / 256, 256, 0, stream>>>(pde, rbs);
    mask_scan<<<dim3(32, 32, 2), 256, 0, stream>>>(msk, flags);

    gemm_qkv<<<dim3(64, 24), 256, 0, stream>>>(xb, wqb, wkb, wvb,
                                               bq, bk, bv, q_bf, k_bf, vt);

    attn2<<<2048, 64, 0, stream>>>(q_bf, k_bf, vt, rbs, msk, flags, aob);

    gemm_out<<<dim3(64, 8), 256, 0, stream>>>(aob, wob, bo, out);
}

// Round 4
// 105.462 us; speedup vs baseline: 4.7402x; 1.5457x over previous
//
#include <hip/hip_runtime.h>
#include <math.h>

#define B_ 2
#define N_ 2048
#define H_ 8
#define DH_ 64
#define DM_ 512
#define R_ 16
#define LAM_ 1.0f
#define SCALE_ 0.125f   // 1/sqrt(64)

typedef unsigned short u16;
typedef u16 u16x4 __attribute__((ext_vector_type(4)));
typedef u16 u16x8 __attribute__((ext_vector_type(8)));
typedef __bf16 bf16x8 __attribute__((ext_vector_type(8)));
typedef float f32x4 __attribute__((ext_vector_type(4)));

static __device__ __forceinline__ u16 f2bf(float f) {
    union { float f; unsigned u; } v; v.f = f;
    unsigned r = v.u + 0x7FFF + ((v.u >> 16) & 1);   // RNE
    return (u16)(r >> 16);
}

static __device__ __forceinline__ void gl_lds16(const void* g, void* l) {
    __builtin_amdgcn_global_load_lds(
        (const __attribute__((address_space(1))) unsigned*)g,
        (__attribute__((address_space(3))) unsigned*)l, 16, 0, 0);
}

// ---------------------------------------------------------------------------
// bf16 casts: y=0 -> x (2M), y=1..4 -> Wq,Wk,Wv,Wo (256K each)
// ---------------------------------------------------------------------------
__global__ __launch_bounds__(256) void cast_all(
    const float* __restrict__ x, const float* __restrict__ wq,
    const float* __restrict__ wk, const float* __restrict__ wv,
    const float* __restrict__ wo, u16* __restrict__ xb, u16* __restrict__ wqb,
    u16* __restrict__ wkb, u16* __restrict__ wvb, u16* __restrict__ wob) {
    int y = blockIdx.y;
    const float* src; u16* dst; int n;
    switch (y) {
        case 0: src = x;  dst = xb;  n = 2097152; break;
        case 1: src = wq; dst = wqb; n = 262144;  break;
        case 2: src = wk; dst = wkb; n = 262144;  break;
        case 3: src = wv; dst = wvb; n = 262144;  break;
        default: src = wo; dst = wob; n = 262144; break;
    }
    int i = (blockIdx.x * 256 + threadIdx.x) * 8;
    if (i >= n) return;
    float4 a = *(const float4*)(src + i);
    float4 b = *(const float4*)(src + i + 4);
    u16x8 o;
    o[0] = f2bf(a.x); o[1] = f2bf(a.y); o[2] = f2bf(a.z); o[3] = f2bf(a.w);
    o[4] = f2bf(b.x); o[5] = f2bf(b.y); o[6] = f2bf(b.z); o[7] = f2bf(b.w);
    *(u16x8*)(dst + i) = o;
}

// ---------------------------------------------------------------------------
__global__ void rb_kernel(const float* __restrict__ pde, float* __restrict__ rbs) {
    int i = blockIdx.x * blockDim.x + threadIdx.x;
    if (i >= B_ * N_) return;
    const float4* p = (const float4*)(pde + (size_t)i * R_);
    float s = 0.f;
#pragma unroll
    for (int j = 0; j < 4; ++j) {
        float4 v = p[j];
        s += v.x * v.x + v.y * v.y + v.z * v.z + v.w * v.w;
    }
    rbs[i] = LAM_ * sqrtf(s);
}

// ---------------------------------------------------------------------------
__global__ __launch_bounds__(256) void mask_scan(const int* __restrict__ mask,
                                                 int* __restrict__ flags) {
    int kt = blockIdx.x, qt = blockIdx.y, b = blockIdx.z;
    __shared__ int red;
    if (threadIdx.x == 0) red = 0;
    __syncthreads();
    int any = 0;
    for (int c = threadIdx.x; c < 1024; c += 256) {
        int row = c >> 4, seg = c & 15;
        int4 m4 = *(const int4*)(mask + (size_t)b * N_ * N_ +
                                 (size_t)(qt * 64 + row) * N_ + kt * 64 + seg * 4);
        any |= (m4.x == 0) | (m4.y == 0) | (m4.z == 0) | (m4.w == 0);
    }
    if (__ballot(any)) {
        if ((threadIdx.x & 63) == 0) atomicOr(&red, 1);
    }
    __syncthreads();
    if (threadIdx.x == 0) flags[(b * 32 + qt) * 32 + kt] = red;
}

// ---------------------------------------------------------------------------
// bf16 MFMA GEMM core (m97 pattern): 64x64 tile, BK=64, 4 waves 32x32 each.
// LDS linear dest + pre-swizzled global source + swizzled ds_read (T2/#21).
// ---------------------------------------------------------------------------
struct Acc { f32x4 v[2][2]; };

static __device__ __forceinline__ Acc gemm_core(const u16* __restrict__ A,
                                                const u16* __restrict__ W,
                                                int m0, int nn0, char* LDSB) {
    int t = threadIdx.x, l = t & 63, w = t >> 6;
    int lg = l >> 4, li = l & 15;
    int wr = w >> 1, wc = w & 1;
    Acc acc;
#pragma unroll
    for (int m = 0; m < 2; ++m)
#pragma unroll
        for (int n = 0; n < 2; ++n) acc.v[m][n] = (f32x4){0.f, 0.f, 0.f, 0.f};

    int srow_l = l >> 3;
    int colb = ((l & 7) * 16) ^ (srow_l << 4);   // pre-swizzled source col (bytes)

    for (int k0 = 0; k0 < DM_; k0 += 64) {
        __syncthreads();
#pragma unroll
        for (int i = 0; i < 2; ++i) {
            int c = w * 2 + i;
            int row = c * 8 + srow_l;
            gl_lds16(A + (size_t)(m0 + row) * DM_ + k0 + (colb >> 1),
                     LDSB + c * 1024);
            gl_lds16(W + (size_t)(nn0 + row) * DM_ + k0 + (colb >> 1),
                     LDSB + 8192 + c * 1024);
        }
        __syncthreads();
#pragma unroll
        for (int kk = 0; kk < 2; ++kk) {
            bf16x8 af[2], bfr[2];
#pragma unroll
            for (int m = 0; m < 2; ++m) {
                int r = wr * 32 + m * 16 + li;
                af[m] = *(const bf16x8*)(LDSB + r * 128 +
                                         ((kk * 64 + lg * 16) ^ ((r & 7) << 4)));
            }
#pragma unroll
            for (int n = 0; n < 2; ++n) {
                int r = wc * 32 + n * 16 + li;
                bfr[n] = *(const bf16x8*)(LDSB + 8192 + r * 128 +
                                          ((kk * 64 + lg * 16) ^ ((r & 7) << 4)));
            }
#pragma unroll
            for (int m = 0; m < 2; ++m)
#pragma unroll
                for (int n = 0; n < 2; ++n)
                    acc.v[m][n] = __builtin_amdgcn_mfma_f32_16x16x32_bf16(
                        af[m], bfr[n], acc.v[m][n], 0, 0, 0);
        }
    }
    return acc;
}

// ---------------------------------------------------------------------------
// Fused QKV GEMM. grid (64, 24): y>>3 = 0:Q 1:K 2:V
// ---------------------------------------------------------------------------
__global__ __launch_bounds__(256) void gemm_qkv(
    const u16* __restrict__ xb, const u16* __restrict__ wqb,
    const u16* __restrict__ wkb, const u16* __restrict__ wvb,
    const float* __restrict__ bq, const float* __restrict__ bk,
    const float* __restrict__ bv, u16* __restrict__ q_bf,
    u16* __restrict__ k_bf, u16* __restrict__ vt) {
    __shared__ char LDSB[24576];
    int y = blockIdx.y;
    int which = y >> 3;
    int nn0 = (y & 7) * 64;
    const u16* W = which == 0 ? wqb : which == 1 ? wkb : wvb;
    const float* bias = which == 0 ? bq : which == 1 ? bk : bv;
    int m0 = blockIdx.x * 64;
    Acc acc = gemm_core(xb, W, m0, nn0, LDSB);

    int t = threadIdx.x, l = t & 63, w = t >> 6;
    int lg = l >> 4, li = l & 15;
    int wr = w >> 1, wc = w & 1;
    float scale = which == 0 ? SCALE_ : 1.0f;
#pragma unroll
    for (int n = 0; n < 2; ++n) {
        int col = nn0 + wc * 32 + n * 16 + li;
        float bv_ = bias[col];
        if (which < 2) {
            u16* dst = which == 0 ? q_bf : k_bf;
#pragma unroll
            for (int m = 0; m < 2; ++m)
#pragma unroll
                for (int r = 0; r < 4; ++r) {
                    int row = m0 + wr * 32 + m * 16 + lg * 4 + r;
                    dst[(size_t)row * DM_ + col] =
                        f2bf((acc.v[m][n][r] + bv_) * scale);
                }
        } else {
            int h = col >> 6, d = col & 63;
#pragma unroll
            for (int m = 0; m < 2; ++m) {
                int row = m0 + wr * 32 + m * 16 + lg * 4;
                int b = row >> 11, nb = row & (N_ - 1);
                u16x4 o;
#pragma unroll
                for (int r = 0; r < 4; ++r) o[r] = f2bf(acc.v[m][n][r] + bv_);
                *(u16x4*)(vt + ((size_t)((b * 8 + h) * 64 + d)) * N_ + nb) = o;
            }
        }
    }
}

// ---------------------------------------------------------------------------
__global__ __launch_bounds__(256) void gemm_out(
    const u16* __restrict__ aob, const u16* __restrict__ wob,
    const float* __restrict__ bo, float* __restrict__ out) {
    __shared__ char LDSB[24576];
    int nn0 = blockIdx.y * 64;
    int m0 = blockIdx.x * 64;
    Acc acc = gemm_core(aob, wob, m0, nn0, LDSB);

    int t = threadIdx.x, l = t & 63, w = t >> 6;
    int lg = l >> 4, li = l & 15;
    int wr = w >> 1, wc = w & 1;
#pragma unroll
    for (int n = 0; n < 2; ++n) {
        int col = nn0 + wc * 32 + n * 16 + li;
        float bv_ = bo[col];
#pragma unroll
        for (int m = 0; m < 2; ++m)
#pragma unroll
            for (int r = 0; r < 4; ++r) {
                int row = m0 + wr * 32 + m * 16 + lg * 4 + r;
                out[(size_t)row * DM_ + col] = acc.v[m][n][r] + bv_;
            }
    }
}

// ---------------------------------------------------------------------------
// attn3: 4 waves x 16 q-rows (64-row block), K/V tile SHARED via LDS,
// double-buffered, prefetch-before-compute (T3-min), one barrier/tile.
// K tile [64 key][64 d] + V^T tile [64 d][64 key], both XOR-swizzled via
// pre-swizzled global_load_lds source (rule #21). P wave-private (no barrier).
// ---------------------------------------------------------------------------
__global__ __launch_bounds__(256) void attn3(
    const u16* __restrict__ qb, const u16* __restrict__ kb,
    const u16* __restrict__ vtb, const float* __restrict__ rbs,
    const int* __restrict__ mask, const int* __restrict__ flags,
    u16* __restrict__ aob) {
    __shared__ char KVB[2][16384];   // [buf][0..8191 K | 8192..16383 V^T]
    __shared__ char PsB[4][2048];

    int t = threadIdx.x, l = t & 63, w = t >> 6;
    int raw = blockIdx.x;
    int sid = (raw & 7) * 64 + (raw >> 3);   // XCD-contiguous (512 % 8 == 0)
    int bh = sid >> 5, qg = sid & 31;        // 32 blocks per bh stay on one XCD
    int b = bh >> 3, h = bh & 7;
    int m0 = qg * 64 + w * 16;               // this wave's 16 q-rows
    int lg = l >> 4, li = l & 15;

    int srl = l >> 3;
    int colb = ((l & 7) * 16) ^ (srl << 4);  // pre-swizzled source col (bytes)

    // Q fragments
    bf16x8 qa[2];
    {
        const u16* qrow = qb + (size_t)(b * N_ + m0 + li) * DM_ + h * DH_;
        qa[0] = __builtin_bit_cast(bf16x8, *(const u16x8*)(qrow + lg * 8));
        qa[1] = __builtin_bit_cast(bf16x8, *(const u16x8*)(qrow + 32 + lg * 8));
    }

    f32x4 o[4];
#pragma unroll
    for (int dt = 0; dt < 4; ++dt) o[dt] = (f32x4){0.f, 0.f, 0.f, 0.f};
    float mrun[4], lrun[4];
#pragma unroll
    for (int r = 0; r < 4; ++r) { mrun[r] = -INFINITY; lrun[r] = 0.f; }

    auto STAGE = [&](int bufi, int k0s) {
        char* base = &KVB[bufi][0];
#pragma unroll
        for (int c = 0; c < 2; ++c) {
            int chunk = w * 2 + c;
            int row = chunk * 8 + srl;
            gl_lds16(kb + (size_t)(b * N_ + k0s + row) * DM_ + h * DH_ + (colb >> 1),
                     base + chunk * 1024);
            gl_lds16(vtb + ((size_t)(bh * DH_ + row)) * N_ + k0s + (colb >> 1),
                     base + 8192 + chunk * 1024);
        }
    };

    STAGE(0, 0);
    __syncthreads();

    int buf = 0;
    for (int tt = 0; tt < N_ / 64; ++tt) {
        int k0 = tt * 64;
        if (tt < N_ / 64 - 1) STAGE(buf ^ 1, k0 + 64);   // prefetch next tile

        const char* Kb = &KVB[buf][0];
        const char* Vb = &KVB[buf][8192];
        int flag = flags[(b * 32 + (m0 >> 6)) * 32 + (k0 >> 6)];

        // ---- S = Q.K^T ----
        f32x4 st[4];
        __builtin_amdgcn_s_setprio(1);
#pragma unroll
        for (int kt = 0; kt < 4; ++kt) {
            st[kt] = (f32x4){0.f, 0.f, 0.f, 0.f};
#pragma unroll
            for (int s = 0; s < 2; ++s) {
                int key = kt * 16 + li;
                bf16x8 kf = *(const bf16x8*)(Kb + key * 128 +
                                             ((s * 64 + lg * 16) ^ ((key & 7) << 4)));
                st[kt] = __builtin_amdgcn_mfma_f32_16x16x32_bf16(qa[s], kf, st[kt],
                                                                 0, 0, 0);
            }
        }
        __builtin_amdgcn_s_setprio(0);

        // ---- bias + (rare) mask ----
#pragma unroll
        for (int kt = 0; kt < 4; ++kt) {
            float rbv = rbs[b * N_ + k0 + kt * 16 + li];
#pragma unroll
            for (int r = 0; r < 4; ++r) st[kt][r] -= rbv;
        }
        if (flag) {
#pragma unroll
            for (int kt = 0; kt < 4; ++kt)
#pragma unroll
                for (int r = 0; r < 4; ++r) {
                    int rowg = m0 + lg * 4 + r;
                    int keyg = k0 + kt * 16 + li;
                    if (mask[(size_t)b * N_ * N_ + (size_t)rowg * N_ + keyg] == 0)
                        st[kt][r] = -INFINITY;
                }
        }

        // ---- online softmax ----
        float mloc[4];
#pragma unroll
        for (int r = 0; r < 4; ++r)
            mloc[r] = fmaxf(fmaxf(st[0][r], st[1][r]), fmaxf(st[2][r], st[3][r]));
#pragma unroll
        for (int off = 1; off < 16; off <<= 1)
#pragma unroll
            for (int r = 0; r < 4; ++r)
                mloc[r] = fmaxf(mloc[r], __shfl_xor(mloc[r], off, 16));

        float corr[4], psum[4];
#pragma unroll
        for (int r = 0; r < 4; ++r) {
            float mnew = fmaxf(fmaxf(mrun[r], mloc[r]), -3.0e38f);
            corr[r] = __expf(mrun[r] - mnew);
            mrun[r] = mnew;
            psum[r] = 0.f;
        }
#pragma unroll
        for (int kt = 0; kt < 4; ++kt)
#pragma unroll
            for (int r = 0; r < 4; ++r) {
                float p = __expf(st[kt][r] - mrun[r]);
                psum[r] += p;
                int prow = lg * 4 + r, key = kt * 16 + li;
                *(u16*)(&PsB[w][0] +
                        ((prow * 128 + key * 2) ^ ((prow & 7) << 4))) = f2bf(p);
            }
#pragma unroll
        for (int off = 1; off < 16; off <<= 1)
#pragma unroll
            for (int r = 0; r < 4; ++r) psum[r] += __shfl_xor(psum[r], off, 16);
#pragma unroll
        for (int r = 0; r < 4; ++r) lrun[r] = lrun[r] * corr[r] + psum[r];
#pragma unroll
        for (int dt = 0; dt < 4; ++dt)
#pragma unroll
            for (int r = 0; r < 4; ++r) o[dt][r] *= corr[r];

        // ---- O += P @ V ----
        bf16x8 pf[2];
#pragma unroll
        for (int s = 0; s < 2; ++s)
            pf[s] = *(const bf16x8*)(&PsB[w][0] +
                                     ((li * 128 + s * 64 + lg * 16) ^
                                      ((li & 7) << 4)));
        __builtin_amdgcn_s_setprio(1);
#pragma unroll
        for (int dt = 0; dt < 4; ++dt)
#pragma unroll
            for (int s = 0; s < 2; ++s) {
                int d = dt * 16 + li;
                bf16x8 vf = *(const bf16x8*)(Vb + d * 128 +
                                             ((s * 64 + lg * 16) ^ ((d & 7) << 4)));
                o[dt] = __builtin_amdgcn_mfma_f32_16x16x32_bf16(pf[s], vf, o[dt],
                                                                0, 0, 0);
            }
        __builtin_amdgcn_s_setprio(0);

        __syncthreads();   // own prefetch drained (vmcnt) + all waves done with buf
        buf ^= 1;
    }

    float inv[4];
#pragma unroll
    for (int r = 0; r < 4; ++r) inv[r] = 1.f / lrun[r];
#pragma unroll
    for (int dt = 0; dt < 4; ++dt)
#pragma unroll
        for (int r = 0; r < 4; ++r)
            aob[(size_t)(b * N_ + m0 + lg * 4 + r) * DM_ + h * DH_ + dt * 16 + li] =
                f2bf(o[dt][r] * inv[r]);
}

// ---------------------------------------------------------------------------
extern "C" void kernel_launch(void* const* d_in, const int* in_sizes, int n_in,
                              void* d_out, int out_size, void* d_ws, size_t ws_size,
                              hipStream_t stream) {
    const float* x   = (const float*)d_in[0];
    const float* pde = (const float*)d_in[1];
    const int*   msk = (const int*)d_in[2];
    const float* Wq  = (const float*)d_in[3];
    const float* bq  = (const float*)d_in[4];
    const float* Wk  = (const float*)d_in[5];
    const float* bk  = (const float*)d_in[6];
    const float* Wv  = (const float*)d_in[7];
    const float* bv  = (const float*)d_in[8];
    const float* Wo  = (const float*)d_in[9];
    const float* bo  = (const float*)d_in[10];
    float* out = (float*)d_out;

    const size_t MAT = (size_t)B_ * N_ * DM_;
    const size_t WSZ = (size_t)DM_ * DM_;
    u16* xb   = (u16*)d_ws;
    u16* q_bf = xb + MAT;
    u16* k_bf = q_bf + MAT;
    u16* vt   = k_bf + MAT;
    u16* aob  = vt + MAT;
    u16* wqb  = aob + MAT;
    u16* wkb  = wqb + WSZ;
    u16* wvb  = wkb + WSZ;
    u16* wob  = wvb + WSZ;
    float* rbs = (float*)(wob + WSZ);
    int* flags = (int*)(rbs + B_ * N_);

    cast_all<<<dim3(1024, 5), 256, 0, stream>>>(x, Wq, Wk, Wv, Wo,
                                                xb, wqb, wkb, wvb, wob);
    rb_kernel<<<(B_ * N_ + 255) / 256, 256, 0, stream>>>(pde, rbs);
    mask_scan<<<dim3(32, 32, 2), 256, 0, stream>>>(msk, flags);

    gemm_qkv<<<dim3(64, 24), 256, 0, stream>>>(xb, wqb, wkb, wvb,
                                               bq, bk, bv, q_bf, k_bf, vt);

    attn3<<<512, 256, 0, stream>>>(q_bf, k_bf, vt, rbs, msk, flags, aob);

    gemm_out<<<dim3(64, 8), 256, 0, stream>>>(aob, wob, bo, out);
}

// Round 7
// 93.406 us; speedup vs baseline: 5.3520x; 1.1291x over previous
//
#include <hip/hip_runtime.h>
#include <math.h>

#define B_ 2
#define N_ 2048
#define H_ 8
#define DH_ 64
#define DM_ 512
#define R_ 16
#define LAM_ 1.0f
#define SCALE_ 0.125f   // 1/sqrt(64)

typedef unsigned short u16;
typedef unsigned int u32;
typedef u16 u16x4 __attribute__((ext_vector_type(4)));
typedef u16 u16x8 __attribute__((ext_vector_type(8)));
typedef __bf16 bf16x8 __attribute__((ext_vector_type(8)));
typedef float f32x4 __attribute__((ext_vector_type(4)));

static __device__ __forceinline__ u16 f2bf(float f) {
    union { float f; unsigned u; } v; v.f = f;
    unsigned r = v.u + 0x7FFF + ((v.u >> 16) & 1);   // RNE
    return (u16)(r >> 16);
}

static __device__ __forceinline__ void gl_lds16(const void* g, void* l) {
    __builtin_amdgcn_global_load_lds(
        (const __attribute__((address_space(1))) unsigned*)g,
        (__attribute__((address_space(3))) unsigned*)l, 16, 0, 0);
}

// ---------------------------------------------------------------------------
// bf16 casts: y=0 -> x (2M), y=1..4 -> Wq,Wk,Wv,Wo (256K each)
// ---------------------------------------------------------------------------
__global__ __launch_bounds__(256) void cast_all(
    const float* __restrict__ x, const float* __restrict__ wq,
    const float* __restrict__ wk, const float* __restrict__ wv,
    const float* __restrict__ wo, u16* __restrict__ xb, u16* __restrict__ wqb,
    u16* __restrict__ wkb, u16* __restrict__ wvb, u16* __restrict__ wob) {
    int y = blockIdx.y;
    const float* src; u16* dst; int n;
    switch (y) {
        case 0: src = x;  dst = xb;  n = 2097152; break;
        case 1: src = wq; dst = wqb; n = 262144;  break;
        case 2: src = wk; dst = wkb; n = 262144;  break;
        case 3: src = wv; dst = wvb; n = 262144;  break;
        default: src = wo; dst = wob; n = 262144; break;
    }
    int i = (blockIdx.x * 256 + threadIdx.x) * 8;
    if (i >= n) return;
    float4 a = *(const float4*)(src + i);
    float4 b = *(const float4*)(src + i + 4);
    u16x8 o;
    o[0] = f2bf(a.x); o[1] = f2bf(a.y); o[2] = f2bf(a.z); o[3] = f2bf(a.w);
    o[4] = f2bf(b.x); o[5] = f2bf(b.y); o[6] = f2bf(b.z); o[7] = f2bf(b.w);
    *(u16x8*)(dst + i) = o;
}

// ---------------------------------------------------------------------------
__global__ void rb_kernel(const float* __restrict__ pde, float* __restrict__ rbs) {
    int i = blockIdx.x * blockDim.x + threadIdx.x;
    if (i >= B_ * N_) return;
    const float4* p = (const float4*)(pde + (size_t)i * R_);
    float s = 0.f;
#pragma unroll
    for (int j = 0; j < 4; ++j) {
        float4 v = p[j];
        s += v.x * v.x + v.y * v.y + v.z * v.z + v.w * v.w;
    }
    rbs[i] = LAM_ * sqrtf(s);
}

// ---------------------------------------------------------------------------
__global__ __launch_bounds__(256) void mask_scan(const int* __restrict__ mask,
                                                 int* __restrict__ flags) {
    int kt = blockIdx.x, qt = blockIdx.y, b = blockIdx.z;
    __shared__ int red;
    if (threadIdx.x == 0) red = 0;
    __syncthreads();
    int any = 0;
    for (int c = threadIdx.x; c < 1024; c += 256) {
        int row = c >> 4, seg = c & 15;
        int4 m4 = *(const int4*)(mask + (size_t)b * N_ * N_ +
                                 (size_t)(qt * 64 + row) * N_ + kt * 64 + seg * 4);
        any |= (m4.x == 0) | (m4.y == 0) | (m4.z == 0) | (m4.w == 0);
    }
    if (__ballot(any)) {
        if ((threadIdx.x & 63) == 0) atomicOr(&red, 1);
    }
    __syncthreads();
    if (threadIdx.x == 0) flags[(b * 32 + qt) * 32 + kt] = red;
}

// ---------------------------------------------------------------------------
// bf16 MFMA GEMM core (m97 pattern): 64x64 tile, BK=64, 4 waves 32x32 each.
// ---------------------------------------------------------------------------
struct Acc { f32x4 v[2][2]; };

static __device__ __forceinline__ Acc gemm_core(const u16* __restrict__ A,
                                                const u16* __restrict__ W,
                                                int m0, int nn0, char* LDSB) {
    int t = threadIdx.x, l = t & 63, w = t >> 6;
    int lg = l >> 4, li = l & 15;
    int wr = w >> 1, wc = w & 1;
    Acc acc;
#pragma unroll
    for (int m = 0; m < 2; ++m)
#pragma unroll
        for (int n = 0; n < 2; ++n) acc.v[m][n] = (f32x4){0.f, 0.f, 0.f, 0.f};

    int srow_l = l >> 3;
    int colb = ((l & 7) * 16) ^ (srow_l << 4);   // pre-swizzled source col (bytes)

    for (int k0 = 0; k0 < DM_; k0 += 64) {
        __syncthreads();
#pragma unroll
        for (int i = 0; i < 2; ++i) {
            int c = w * 2 + i;
            int row = c * 8 + srow_l;
            gl_lds16(A + (size_t)(m0 + row) * DM_ + k0 + (colb >> 1),
                     LDSB + c * 1024);
            gl_lds16(W + (size_t)(nn0 + row) * DM_ + k0 + (colb >> 1),
                     LDSB + 8192 + c * 1024);
        }
        __syncthreads();
#pragma unroll
        for (int kk = 0; kk < 2; ++kk) {
            bf16x8 af[2], bfr[2];
#pragma unroll
            for (int m = 0; m < 2; ++m) {
                int r = wr * 32 + m * 16 + li;
                af[m] = *(const bf16x8*)(LDSB + r * 128 +
                                         ((kk * 64 + lg * 16) ^ ((r & 7) << 4)));
            }
#pragma unroll
            for (int n = 0; n < 2; ++n) {
                int r = wc * 32 + n * 16 + li;
                bfr[n] = *(const bf16x8*)(LDSB + 8192 + r * 128 +
                                          ((kk * 64 + lg * 16) ^ ((r & 7) << 4)));
            }
#pragma unroll
            for (int m = 0; m < 2; ++m)
#pragma unroll
                for (int n = 0; n < 2; ++n)
                    acc.v[m][n] = __builtin_amdgcn_mfma_f32_16x16x32_bf16(
                        af[m], bfr[n], acc.v[m][n], 0, 0, 0);
        }
    }
    return acc;
}

// ---------------------------------------------------------------------------
// Fused QKV GEMM. grid (64, 24): y>>3 = 0:Q 1:K 2:V
// ---------------------------------------------------------------------------
__global__ __launch_bounds__(256) void gemm_qkv(
    const u16* __restrict__ xb, const u16* __restrict__ wqb,
    const u16* __restrict__ wkb, const u16* __restrict__ wvb,
    const float* __restrict__ bq, const float* __restrict__ bk,
    const float* __restrict__ bv, u16* __restrict__ q_bf,
    u16* __restrict__ k_bf, u16* __restrict__ vt) {
    __shared__ char LDSB[24576];
    int y = blockIdx.y;
    int which = y >> 3;
    int nn0 = (y & 7) * 64;
    const u16* W = which == 0 ? wqb : which == 1 ? wkb : wvb;
    const float* bias = which == 0 ? bq : which == 1 ? bk : bv;
    int m0 = blockIdx.x * 64;
    Acc acc = gemm_core(xb, W, m0, nn0, LDSB);

    int t = threadIdx.x, l = t & 63, w = t >> 6;
    int lg = l >> 4, li = l & 15;
    int wr = w >> 1, wc = w & 1;
    float scale = which == 0 ? SCALE_ : 1.0f;
#pragma unroll
    for (int n = 0; n < 2; ++n) {
        int col = nn0 + wc * 32 + n * 16 + li;
        float bv_ = bias[col];
        if (which < 2) {
            u16* dst = which == 0 ? q_bf : k_bf;
#pragma unroll
            for (int m = 0; m < 2; ++m)
#pragma unroll
                for (int r = 0; r < 4; ++r) {
                    int row = m0 + wr * 32 + m * 16 + lg * 4 + r;
                    dst[(size_t)row * DM_ + col] =
                        f2bf((acc.v[m][n][r] + bv_) * scale);
                }
        } else {
            int h = col >> 6, d = col & 63;
#pragma unroll
            for (int m = 0; m < 2; ++m) {
                int row = m0 + wr * 32 + m * 16 + lg * 4;
                int b = row >> 11, nb = row & (N_ - 1);
                u16x4 o;
#pragma unroll
                for (int r = 0; r < 4; ++r) o[r] = f2bf(acc.v[m][n][r] + bv_);
                *(u16x4*)(vt + ((size_t)((b * 8 + h) * 64 + d)) * N_ + nb) = o;
            }
        }
    }
}

// ---------------------------------------------------------------------------
__global__ __launch_bounds__(256) void gemm_out(
    const u16* __restrict__ aob, const u16* __restrict__ wob,
    const float* __restrict__ bo, float* __restrict__ out) {
    __shared__ char LDSB[24576];
    int nn0 = blockIdx.y * 64;
    int m0 = blockIdx.x * 64;
    Acc acc = gemm_core(aob, wob, m0, nn0, LDSB);

    int t = threadIdx.x, l = t & 63, w = t >> 6;
    int lg = l >> 4, li = l & 15;
    int wr = w >> 1, wc = w & 1;
#pragma unroll
    for (int n = 0; n < 2; ++n) {
        int col = nn0 + wc * 32 + n * 16 + li;
        float bv_ = bo[col];
#pragma unroll
        for (int m = 0; m < 2; ++m)
#pragma unroll
            for (int r = 0; r < 4; ++r) {
                int row = m0 + wr * 32 + m * 16 + lg * 4 + r;
                out[(size_t)row * DM_ + col] = acc.v[m][n][r] + bv_;
            }
    }
}

// ---------------------------------------------------------------------------
// attn6 (BISECTION): attn3's verified inner loop VERBATIM (unswapped mfma,
// width-16 shfl softmax, scalar P writes) + in-block K-split x2:
// 512 threads = 2 groups x 4 waves; group g2 owns keys g2*1024..+1023 with
// its own double-buffered KV LDS; partials merged through dead LDS.
// ---------------------------------------------------------------------------
__global__ __launch_bounds__(512) void attn6(
    const u16* __restrict__ qb, const u16* __restrict__ kb,
    const u16* __restrict__ vtb, const float* __restrict__ rbs,
    const int* __restrict__ mask, const int* __restrict__ flags,
    u16* __restrict__ aob) {
    __shared__ char KVB[2][2][16384];   // [group][buf][0..8191 K | 8192.. V^T]
    __shared__ char PsB[8][2048];

    int t = threadIdx.x, l = t & 63, w = t >> 6;   // w 0..7
    int g2 = w >> 2, wq = w & 3;
    int raw = blockIdx.x;
    int sid = (raw & 7) * 64 + (raw >> 3);   // XCD-contiguous (512 % 8 == 0)
    int bh = sid >> 5, qg = sid & 31;
    int b = bh >> 3, h = bh & 7;
    int m0 = qg * 64 + wq * 16;              // this wave's 16 q-rows
    int lg = l >> 4, li = l & 15;
    int k0base = g2 * 1024;

    int srl = l >> 3;
    int colb = ((l & 7) * 16) ^ (srl << 4);  // pre-swizzled source col (bytes)

    // Q fragments (A-operand): lane holds Q[row=li][d = s*32 + lg*8 + j]
    bf16x8 qa[2];
    {
        const u16* qrow = qb + (size_t)(b * N_ + m0 + li) * DM_ + h * DH_;
        qa[0] = __builtin_bit_cast(bf16x8, *(const u16x8*)(qrow + lg * 8));
        qa[1] = __builtin_bit_cast(bf16x8, *(const u16x8*)(qrow + 32 + lg * 8));
    }

    f32x4 o[4];   // o[dt][r] = O[qrow=m0+lg*4+r][d=dt*16+li]  (unnormalized)
#pragma unroll
    for (int dt = 0; dt < 4; ++dt) o[dt] = (f32x4){0.f, 0.f, 0.f, 0.f};
    float mrun[4], lrun[4];
#pragma unroll
    for (int r = 0; r < 4; ++r) { mrun[r] = -INFINITY; lrun[r] = 0.f; }

    auto STAGE = [&](int bufi, int k0s) {
        char* base = &KVB[g2][bufi][0];
#pragma unroll
        for (int c = 0; c < 2; ++c) {
            int chunk = wq * 2 + c;
            int row = chunk * 8 + srl;
            gl_lds16(kb + (size_t)(b * N_ + k0s + row) * DM_ + h * DH_ + (colb >> 1),
                     base + chunk * 1024);
            gl_lds16(vtb + ((size_t)(bh * DH_ + row)) * N_ + k0s + (colb >> 1),
                     base + 8192 + chunk * 1024);
        }
    };

    STAGE(0, k0base);
    __syncthreads();

    int buf = 0;
    for (int tt = 0; tt < 16; ++tt) {
        int k0 = k0base + tt * 64;
        if (tt < 15) STAGE(buf ^ 1, k0 + 64);   // prefetch next tile

        const char* Kb = &KVB[g2][buf][0];
        const char* Vb = &KVB[g2][buf][8192];
        int flag = flags[(b * 32 + qg) * 32 + (k0 >> 6)];

        // ---- S = Q.K^T : st[kt][r] = S[qrow=lg*4+r][key=kt*16+li] ----
        f32x4 st[4];
        __builtin_amdgcn_s_setprio(1);
#pragma unroll
        for (int kt = 0; kt < 4; ++kt) {
            st[kt] = (f32x4){0.f, 0.f, 0.f, 0.f};
#pragma unroll
            for (int s = 0; s < 2; ++s) {
                int key = kt * 16 + li;
                bf16x8 kf = *(const bf16x8*)(Kb + key * 128 +
                                             ((s * 64 + lg * 16) ^ ((key & 7) << 4)));
                st[kt] = __builtin_amdgcn_mfma_f32_16x16x32_bf16(qa[s], kf, st[kt],
                                                                 0, 0, 0);
            }
        }
        __builtin_amdgcn_s_setprio(0);

        // ---- bias + (rare) mask ----
#pragma unroll
        for (int kt = 0; kt < 4; ++kt) {
            float rbv = rbs[b * N_ + k0 + kt * 16 + li];
#pragma unroll
            for (int r = 0; r < 4; ++r) st[kt][r] -= rbv;
        }
        if (flag) {
#pragma unroll
            for (int kt = 0; kt < 4; ++kt)
#pragma unroll
                for (int r = 0; r < 4; ++r) {
                    int rowg = m0 + lg * 4 + r;
                    int keyg = k0 + kt * 16 + li;
                    if (mask[(size_t)b * N_ * N_ + (size_t)rowg * N_ + keyg] == 0)
                        st[kt][r] = -INFINITY;
                }
        }

        // ---- online softmax (rows live in 16-lane groups) ----
        float mloc[4];
#pragma unroll
        for (int r = 0; r < 4; ++r)
            mloc[r] = fmaxf(fmaxf(st[0][r], st[1][r]), fmaxf(st[2][r], st[3][r]));
#pragma unroll
        for (int off = 1; off < 16; off <<= 1)
#pragma unroll
            for (int r = 0; r < 4; ++r)
                mloc[r] = fmaxf(mloc[r], __shfl_xor(mloc[r], off, 16));

        float corr[4], psum[4];
#pragma unroll
        for (int r = 0; r < 4; ++r) {
            float mnew = fmaxf(fmaxf(mrun[r], mloc[r]), -3.0e38f);
            corr[r] = __expf(mrun[r] - mnew);
            mrun[r] = mnew;
            psum[r] = 0.f;
        }
#pragma unroll
        for (int kt = 0; kt < 4; ++kt)
#pragma unroll
            for (int r = 0; r < 4; ++r) {
                float p = __expf(st[kt][r] - mrun[r]);
                psum[r] += p;
                int prow = lg * 4 + r, key = kt * 16 + li;
                *(u16*)(&PsB[w][0] +
                        ((prow * 128 + key * 2) ^ ((prow & 7) << 4))) = f2bf(p);
            }
#pragma unroll
        for (int off = 1; off < 16; off <<= 1)
#pragma unroll
            for (int r = 0; r < 4; ++r) psum[r] += __shfl_xor(psum[r], off, 16);
#pragma unroll
        for (int r = 0; r < 4; ++r) lrun[r] = lrun[r] * corr[r] + psum[r];
#pragma unroll
        for (int dt = 0; dt < 4; ++dt)
#pragma unroll
            for (int r = 0; r < 4; ++r) o[dt][r] *= corr[r];

        // ---- O += P @ V ----
        bf16x8 pf[2];
#pragma unroll
        for (int s = 0; s < 2; ++s)
            pf[s] = *(const bf16x8*)(&PsB[w][0] +
                                     ((li * 128 + s * 64 + lg * 16) ^
                                      ((li & 7) << 4)));
        __builtin_amdgcn_s_setprio(1);
#pragma unroll
        for (int dt = 0; dt < 4; ++dt)
#pragma unroll
            for (int s = 0; s < 2; ++s) {
                int d = dt * 16 + li;
                bf16x8 vf = *(const bf16x8*)(Vb + d * 128 +
                                             ((s * 64 + lg * 16) ^ ((d & 7) << 4)));
                o[dt] = __builtin_amdgcn_mfma_f32_16x16x32_bf16(pf[s], vf, o[dt],
                                                                0, 0, 0);
            }
        __builtin_amdgcn_s_setprio(0);

        __syncthreads();
        buf ^= 1;
    }

    // ---- in-block combine of the two key-splits ----
    // o[dt][r] = O[qrow=m0+lg*4+r][d=dt*16+li]; ml per row lg*4+r (uniform
    // across the 16 li lanes after the width-16 reduce).
    float* cmb = (float*)&KVB[0][0][0];   // 4 waves x [16 rows][64 d] = 16KB
    float* mlc = (float*)&PsB[0][0];      // 64 rows x 2 floats
    if (g2 == 1) {
        float* dst = cmb + wq * 1024;
#pragma unroll
        for (int dt = 0; dt < 4; ++dt)
#pragma unroll
            for (int r = 0; r < 4; ++r)
                dst[(lg * 4 + r) * 64 + dt * 16 + li] = o[dt][r];
        if (li == 0) {
#pragma unroll
            for (int r = 0; r < 4; ++r) {
                float2 ml; ml.x = mrun[r]; ml.y = lrun[r];
                *(float2*)(mlc + (wq * 16 + lg * 4 + r) * 2) = ml;
            }
        }
    }
    __syncthreads();
    if (g2 == 0) {
        const float* src = cmb + wq * 1024;
#pragma unroll
        for (int r = 0; r < 4; ++r) {
            float2 ml1 = *(const float2*)(mlc + (wq * 16 + lg * 4 + r) * 2);
            float m = fmaxf(mrun[r], ml1.x);
            float w0 = __expf(mrun[r] - m), w1 = __expf(ml1.x - m);
            float denom = 1.f / (lrun[r] * w0 + ml1.y * w1);
            w0 *= denom; w1 *= denom;
            u16* orow = aob + (size_t)(b * N_ + m0 + lg * 4 + r) * DM_ + h * DH_;
#pragma unroll
            for (int dt = 0; dt < 4; ++dt) {
                float p1 = src[(lg * 4 + r) * 64 + dt * 16 + li];
                orow[dt * 16 + li] = f2bf(o[dt][r] * w0 + p1 * w1);
            }
        }
    }
}

// ---------------------------------------------------------------------------
extern "C" void kernel_launch(void* const* d_in, const int* in_sizes, int n_in,
                              void* d_out, int out_size, void* d_ws, size_t ws_size,
                              hipStream_t stream) {
    const float* x   = (const float*)d_in[0];
    const float* pde = (const float*)d_in[1];
    const int*   msk = (const int*)d_in[2];
    const float* Wq  = (const float*)d_in[3];
    const float* bq  = (const float*)d_in[4];
    const float* Wk  = (const float*)d_in[5];
    const float* bk  = (const float*)d_in[6];
    const float* Wv  = (const float*)d_in[7];
    const float* bv  = (const float*)d_in[8];
    const float* Wo  = (const float*)d_in[9];
    const float* bo  = (const float*)d_in[10];
    float* out = (float*)d_out;

    const size_t MAT = (size_t)B_ * N_ * DM_;   // 2M elements
    const size_t WSZ = (size_t)DM_ * DM_;
    u16* xb   = (u16*)d_ws;
    u16* q_bf = xb + MAT;
    u16* k_bf = q_bf + MAT;
    u16* vt   = k_bf + MAT;
    u16* aob  = vt + MAT;
    u16* wqb  = aob + MAT;
    u16* wkb  = wqb + WSZ;
    u16* wvb  = wkb + WSZ;
    u16* wob  = wvb + WSZ;
    float* rbs = (float*)(wob + WSZ);
    int* flags = (int*)(rbs + B_ * N_);

    cast_all<<<dim3(1024, 5), 256, 0, stream>>>(x, Wq, Wk, Wv, Wo,
                                                xb, wqb, wkb, wvb, wob);
    rb_kernel<<<(B_ * N_ + 255) / 256, 256, 0, stream>>>(pde, rbs);
    mask_scan<<<dim3(32, 32, 2), 256, 0, stream>>>(msk, flags);

    gemm_qkv<<<dim3(64, 24), 256, 0, stream>>>(xb, wqb, wkb, wvb,
                                               bq, bk, bv, q_bf, k_bf, vt);

    attn6<<<512, 512, 0, stream>>>(q_bf, k_bf, vt, rbs, msk, flags, aob);

    gemm_out<<<dim3(64, 8), 256, 0, stream>>>(aob, wob, bo, out);
}

// Round 8
// 80.138 us; speedup vs baseline: 6.2382x; 1.1656x over previous
//
#include <hip/hip_runtime.h>
#include <math.h>

#define B_ 2
#define N_ 2048
#define H_ 8
#define DH_ 64
#define DM_ 512
#define R_ 16
#define LAM_ 1.0f
#define SCALE_ 0.125f   // 1/sqrt(64)

typedef unsigned short u16;
typedef unsigned int u32;
typedef u16 u16x4 __attribute__((ext_vector_type(4)));
typedef u16 u16x8 __attribute__((ext_vector_type(8)));
typedef __bf16 bf16x8 __attribute__((ext_vector_type(8)));
typedef float f32x4 __attribute__((ext_vector_type(4)));

static __device__ __forceinline__ u16 f2bf(float f) {
    union { float f; unsigned u; } v; v.f = f;
    unsigned r = v.u + 0x7FFF + ((v.u >> 16) & 1);   // RNE
    return (u16)(r >> 16);
}

static __device__ __forceinline__ void gl_lds16(const void* g, void* l) {
    __builtin_amdgcn_global_load_lds(
        (const __attribute__((address_space(1))) unsigned*)g,
        (__attribute__((address_space(3))) unsigned*)l, 16, 0, 0);
}

// ---------------------------------------------------------------------------
// bf16 casts: y=0 -> x (2M), y=1..4 -> Wq,Wk,Wv,Wo (256K each)
// ---------------------------------------------------------------------------
__global__ __launch_bounds__(256) void cast_all(
    const float* __restrict__ x, const float* __restrict__ wq,
    const float* __restrict__ wk, const float* __restrict__ wv,
    const float* __restrict__ wo, u16* __restrict__ xb, u16* __restrict__ wqb,
    u16* __restrict__ wkb, u16* __restrict__ wvb, u16* __restrict__ wob) {
    int y = blockIdx.y;
    const float* src; u16* dst; int n;
    switch (y) {
        case 0: src = x;  dst = xb;  n = 2097152; break;
        case 1: src = wq; dst = wqb; n = 262144;  break;
        case 2: src = wk; dst = wkb; n = 262144;  break;
        case 3: src = wv; dst = wvb; n = 262144;  break;
        default: src = wo; dst = wob; n = 262144; break;
    }
    int i = (blockIdx.x * 256 + threadIdx.x) * 8;
    if (i >= n) return;
    float4 a = *(const float4*)(src + i);
    float4 b = *(const float4*)(src + i + 4);
    u16x8 o;
    o[0] = f2bf(a.x); o[1] = f2bf(a.y); o[2] = f2bf(a.z); o[3] = f2bf(a.w);
    o[4] = f2bf(b.x); o[5] = f2bf(b.y); o[6] = f2bf(b.z); o[7] = f2bf(b.w);
    *(u16x8*)(dst + i) = o;
}

// ---------------------------------------------------------------------------
__global__ void rb_kernel(const float* __restrict__ pde, float* __restrict__ rbs) {
    int i = blockIdx.x * blockDim.x + threadIdx.x;
    if (i >= B_ * N_) return;
    const float4* p = (const float4*)(pde + (size_t)i * R_);
    float s = 0.f;
#pragma unroll
    for (int j = 0; j < 4; ++j) {
        float4 v = p[j];
        s += v.x * v.x + v.y * v.y + v.z * v.z + v.w * v.w;
    }
    rbs[i] = LAM_ * sqrtf(s);
}

// ---------------------------------------------------------------------------
__global__ __launch_bounds__(256) void mask_scan(const int* __restrict__ mask,
                                                 int* __restrict__ flags) {
    int kt = blockIdx.x, qt = blockIdx.y, b = blockIdx.z;
    __shared__ int red;
    if (threadIdx.x == 0) red = 0;
    __syncthreads();
    int any = 0;
    for (int c = threadIdx.x; c < 1024; c += 256) {
        int row = c >> 4, seg = c & 15;
        int4 m4 = *(const int4*)(mask + (size_t)b * N_ * N_ +
                                 (size_t)(qt * 64 + row) * N_ + kt * 64 + seg * 4);
        any |= (m4.x == 0) | (m4.y == 0) | (m4.z == 0) | (m4.w == 0);
    }
    if (__ballot(any)) {
        if ((threadIdx.x & 63) == 0) atomicOr(&red, 1);
    }
    __syncthreads();
    if (threadIdx.x == 0) flags[(b * 32 + qt) * 32 + kt] = red;
}

// ---------------------------------------------------------------------------
// bf16 MFMA GEMM core (m97 pattern): 64x64 tile, BK=64, 4 waves 32x32 each.
// ---------------------------------------------------------------------------
struct Acc { f32x4 v[2][2]; };

static __device__ __forceinline__ Acc gemm_core(const u16* __restrict__ A,
                                                const u16* __restrict__ W,
                                                int m0, int nn0, char* LDSB) {
    int t = threadIdx.x, l = t & 63, w = t >> 6;
    int lg = l >> 4, li = l & 15;
    int wr = w >> 1, wc = w & 1;
    Acc acc;
#pragma unroll
    for (int m = 0; m < 2; ++m)
#pragma unroll
        for (int n = 0; n < 2; ++n) acc.v[m][n] = (f32x4){0.f, 0.f, 0.f, 0.f};

    int srow_l = l >> 3;
    int colb = ((l & 7) * 16) ^ (srow_l << 4);   // pre-swizzled source col (bytes)

    for (int k0 = 0; k0 < DM_; k0 += 64) {
        __syncthreads();
#pragma unroll
        for (int i = 0; i < 2; ++i) {
            int c = w * 2 + i;
            int row = c * 8 + srow_l;
            gl_lds16(A + (size_t)(m0 + row) * DM_ + k0 + (colb >> 1),
                     LDSB + c * 1024);
            gl_lds16(W + (size_t)(nn0 + row) * DM_ + k0 + (colb >> 1),
                     LDSB + 8192 + c * 1024);
        }
        __syncthreads();
#pragma unroll
        for (int kk = 0; kk < 2; ++kk) {
            bf16x8 af[2], bfr[2];
#pragma unroll
            for (int m = 0; m < 2; ++m) {
                int r = wr * 32 + m * 16 + li;
                af[m] = *(const bf16x8*)(LDSB + r * 128 +
                                         ((kk * 64 + lg * 16) ^ ((r & 7) << 4)));
            }
#pragma unroll
            for (int n = 0; n < 2; ++n) {
                int r = wc * 32 + n * 16 + li;
                bfr[n] = *(const bf16x8*)(LDSB + 8192 + r * 128 +
                                          ((kk * 64 + lg * 16) ^ ((r & 7) << 4)));
            }
#pragma unroll
            for (int m = 0; m < 2; ++m)
#pragma unroll
                for (int n = 0; n < 2; ++n)
                    acc.v[m][n] = __builtin_amdgcn_mfma_f32_16x16x32_bf16(
                        af[m], bfr[n], acc.v[m][n], 0, 0, 0);
        }
    }
    return acc;
}

// ---------------------------------------------------------------------------
// Fused QKV GEMM. grid (64, 24): y>>3 = 0:Q 1:K 2:V
// ---------------------------------------------------------------------------
__global__ __launch_bounds__(256) void gemm_qkv(
    const u16* __restrict__ xb, const u16* __restrict__ wqb,
    const u16* __restrict__ wkb, const u16* __restrict__ wvb,
    const float* __restrict__ bq, const float* __restrict__ bk,
    const float* __restrict__ bv, u16* __restrict__ q_bf,
    u16* __restrict__ k_bf, u16* __restrict__ vt) {
    __shared__ char LDSB[24576];
    int y = blockIdx.y;
    int which = y >> 3;
    int nn0 = (y & 7) * 64;
    const u16* W = which == 0 ? wqb : which == 1 ? wkb : wvb;
    const float* bias = which == 0 ? bq : which == 1 ? bk : bv;
    int m0 = blockIdx.x * 64;
    Acc acc = gemm_core(xb, W, m0, nn0, LDSB);

    int t = threadIdx.x, l = t & 63, w = t >> 6;
    int lg = l >> 4, li = l & 15;
    int wr = w >> 1, wc = w & 1;
    float scale = which == 0 ? SCALE_ : 1.0f;
#pragma unroll
    for (int n = 0; n < 2; ++n) {
        int col = nn0 + wc * 32 + n * 16 + li;
        float bv_ = bias[col];
        if (which < 2) {
            u16* dst = which == 0 ? q_bf : k_bf;
#pragma unroll
            for (int m = 0; m < 2; ++m)
#pragma unroll
                for (int r = 0; r < 4; ++r) {
                    int row = m0 + wr * 32 + m * 16 + lg * 4 + r;
                    dst[(size_t)row * DM_ + col] =
                        f2bf((acc.v[m][n][r] + bv_) * scale);
                }
        } else {
            int h = col >> 6, d = col & 63;
#pragma unroll
            for (int m = 0; m < 2; ++m) {
                int row = m0 + wr * 32 + m * 16 + lg * 4;
                int b = row >> 11, nb = row & (N_ - 1);
                u16x4 o;
#pragma unroll
                for (int r = 0; r < 4; ++r) o[r] = f2bf(acc.v[m][n][r] + bv_);
                *(u16x4*)(vt + ((size_t)((b * 8 + h) * 64 + d)) * N_ + nb) = o;
            }
        }
    }
}

// ---------------------------------------------------------------------------
__global__ __launch_bounds__(256) void gemm_out(
    const u16* __restrict__ aob, const u16* __restrict__ wob,
    const float* __restrict__ bo, float* __restrict__ out) {
    __shared__ char LDSB[24576];
    int nn0 = blockIdx.y * 64;
    int m0 = blockIdx.x * 64;
    Acc acc = gemm_core(aob, wob, m0, nn0, LDSB);

    int t = threadIdx.x, l = t & 63, w = t >> 6;
    int lg = l >> 4, li = l & 15;
    int wr = w >> 1, wc = w & 1;
#pragma unroll
    for (int n = 0; n < 2; ++n) {
        int col = nn0 + wc * 32 + n * 16 + li;
        float bv_ = bo[col];
#pragma unroll
        for (int m = 0; m < 2; ++m)
#pragma unroll
            for (int r = 0; r < 4; ++r) {
                int row = m0 + wr * 32 + m * 16 + lg * 4 + r;
                out[(size_t)row * DM_ + col] = acc.v[m][n][r] + bv_;
            }
    }
}

// ---------------------------------------------------------------------------
// attn7 (BISECT step 2): R6's split/combine structure + SWAPPED-operand core.
// mfma(K,Q) -> st[kt][r] = S[key=k0+kt*16+lg*4+r][q=li]; per-lane scalar
// softmax state (q=li); MANUAL bf16 packing (no cvt_pk asm); standard
// always-rescale (no defer-max). mfma(V,P) -> o[dt][r] = O^T[d][q=li].
// ---------------------------------------------------------------------------
__global__ __launch_bounds__(512) void attn7(
    const u16* __restrict__ qb, const u16* __restrict__ kb,
    const u16* __restrict__ vtb, const float* __restrict__ rbs,
    const int* __restrict__ mask, const int* __restrict__ flags,
    u16* __restrict__ aob) {
    __shared__ char KVB[2][2][16384];   // [group][buf][0..8191 K | 8192.. V^T]
    __shared__ char PsB[8][2048];

    int t = threadIdx.x, l = t & 63, w = t >> 6;   // w 0..7
    int g2 = w >> 2, wq = w & 3;
    int raw = blockIdx.x;
    int sid = (raw & 7) * 64 + (raw >> 3);   // XCD-contiguous (512 % 8 == 0)
    int bh = sid >> 5, qg = sid & 31;
    int b = bh >> 3, h = bh & 7;
    int m0 = qg * 64 + wq * 16;              // this wave's 16 q-rows
    int lg = l >> 4, li = l & 15;
    int k0base = g2 * 1024;

    int srl = l >> 3;
    int colb = ((l & 7) * 16) ^ (srl << 4);  // pre-swizzled source col (bytes)

    // Q fragments (B-operand): lane holds Q[qrow=li][d=s*32+lg*8+j]
    bf16x8 qa[2];
    {
        const u16* qrow = qb + (size_t)(b * N_ + m0 + li) * DM_ + h * DH_;
        qa[0] = __builtin_bit_cast(bf16x8, *(const u16x8*)(qrow + lg * 8));
        qa[1] = __builtin_bit_cast(bf16x8, *(const u16x8*)(qrow + 32 + lg * 8));
    }

    f32x4 o[4];   // o[dt][r] = O^T[d=dt*16+lg*4+r][q=li]  (unnormalized)
#pragma unroll
    for (int dt = 0; dt < 4; ++dt) o[dt] = (f32x4){0.f, 0.f, 0.f, 0.f};
    float mrun = -INFINITY, lrun = 0.f;

    auto STAGE = [&](int bufi, int k0s) {
        char* base = &KVB[g2][bufi][0];
#pragma unroll
        for (int c = 0; c < 2; ++c) {
            int chunk = wq * 2 + c;
            int row = chunk * 8 + srl;
            gl_lds16(kb + (size_t)(b * N_ + k0s + row) * DM_ + h * DH_ + (colb >> 1),
                     base + chunk * 1024);
            gl_lds16(vtb + ((size_t)(bh * DH_ + row)) * N_ + k0s + (colb >> 1),
                     base + 8192 + chunk * 1024);
        }
    };

    STAGE(0, k0base);
    __syncthreads();

    int buf = 0;
    for (int tt = 0; tt < 16; ++tt) {
        int k0 = k0base + tt * 64;
        if (tt < 15) STAGE(buf ^ 1, k0 + 64);   // prefetch next tile

        const char* Kb = &KVB[g2][buf][0];
        const char* Vb = &KVB[g2][buf][8192];
        int flag = flags[(b * 32 + qg) * 32 + (k0 >> 6)];

        // ---- S^T = K.Q^T : st[kt][r] = S[key=kt*16+lg*4+r][q=li] ----
        f32x4 st[4];
        __builtin_amdgcn_s_setprio(1);
#pragma unroll
        for (int kt = 0; kt < 4; ++kt) {
            st[kt] = (f32x4){0.f, 0.f, 0.f, 0.f};
#pragma unroll
            for (int s = 0; s < 2; ++s) {
                int key = kt * 16 + li;
                bf16x8 kf = *(const bf16x8*)(Kb + key * 128 +
                                             ((s * 64 + lg * 16) ^ ((key & 7) << 4)));
                st[kt] = __builtin_amdgcn_mfma_f32_16x16x32_bf16(kf, qa[s], st[kt],
                                                                 0, 0, 0);
            }
        }
        __builtin_amdgcn_s_setprio(0);

        // ---- bias (keys consecutive in-lane -> float4 loads) ----
#pragma unroll
        for (int kt = 0; kt < 4; ++kt) {
            float4 rb4 = *(const float4*)(rbs + b * N_ + k0 + kt * 16 + lg * 4);
            st[kt][0] -= rb4.x; st[kt][1] -= rb4.y;
            st[kt][2] -= rb4.z; st[kt][3] -= rb4.w;
        }
        if (flag) {
#pragma unroll
            for (int kt = 0; kt < 4; ++kt)
#pragma unroll
                for (int r = 0; r < 4; ++r) {
                    int rowg = m0 + li;
                    int keyg = k0 + kt * 16 + lg * 4 + r;
                    if (mask[(size_t)b * N_ * N_ + (size_t)rowg * N_ + keyg] == 0)
                        st[kt][r] = -INFINITY;
                }
        }

        // ---- per-lane row max (in-lane tree + shfl over the lg quartet) ----
        float m0_ = fmaxf(fmaxf(st[0][0], st[0][1]), fmaxf(st[0][2], st[0][3]));
        float m1_ = fmaxf(fmaxf(st[1][0], st[1][1]), fmaxf(st[1][2], st[1][3]));
        float m2_ = fmaxf(fmaxf(st[2][0], st[2][1]), fmaxf(st[2][2], st[2][3]));
        float m3_ = fmaxf(fmaxf(st[3][0], st[3][1]), fmaxf(st[3][2], st[3][3]));
        float pmax = fmaxf(fmaxf(m0_, m1_), fmaxf(m2_, m3_));
        pmax = fmaxf(pmax, __shfl_xor(pmax, 16));
        pmax = fmaxf(pmax, __shfl_xor(pmax, 32));

        // ---- standard online rescale (NO defer-max this round) ----
        float mnew = fmaxf(fmaxf(mrun, pmax), -3.0e38f);
        float corr = __expf(mrun - mnew);
        mrun = mnew;
        lrun *= corr;
#pragma unroll
        for (int dt = 0; dt < 4; ++dt)
#pragma unroll
            for (int r = 0; r < 4; ++r) o[dt][r] *= corr;

        // ---- P = exp(S - m), MANUAL bf16 pack, psum tree ----
        float ps[8];
        char* pw = &PsB[w][0] + li * 128;
#pragma unroll
        for (int kt = 0; kt < 4; ++kt) {
            float p0 = __expf(st[kt][0] - mrun);
            float p1 = __expf(st[kt][1] - mrun);
            float p2 = __expf(st[kt][2] - mrun);
            float p3 = __expf(st[kt][3] - mrun);
            ps[kt * 2 + 0] = p0 + p1;
            ps[kt * 2 + 1] = p2 + p3;
            uint2 pkw;
            pkw.x = (u32)f2bf(p0) | ((u32)f2bf(p1) << 16);
            pkw.y = (u32)f2bf(p2) | ((u32)f2bf(p3) << 16);
            *(uint2*)(pw + ((kt * 32 + lg * 8) ^ ((li & 7) << 4))) = pkw;
        }
        float psum = ((ps[0] + ps[1]) + (ps[2] + ps[3])) +
                     ((ps[4] + ps[5]) + (ps[6] + ps[7]));
        psum += __shfl_xor(psum, 16);
        psum += __shfl_xor(psum, 32);
        lrun += psum;

        // ---- O^T += V.P^T ----
        bf16x8 pf[2];
#pragma unroll
        for (int s = 0; s < 2; ++s)
            pf[s] = *(const bf16x8*)(&PsB[w][0] + li * 128 +
                                     ((s * 64 + lg * 16) ^ ((li & 7) << 4)));
        __builtin_amdgcn_s_setprio(1);
#pragma unroll
        for (int dt = 0; dt < 4; ++dt)
#pragma unroll
            for (int s = 0; s < 2; ++s) {
                int d = dt * 16 + li;
                bf16x8 vf = *(const bf16x8*)(Vb + d * 128 +
                                             ((s * 64 + lg * 16) ^ ((d & 7) << 4)));
                o[dt] = __builtin_amdgcn_mfma_f32_16x16x32_bf16(vf, pf[s], o[dt],
                                                                0, 0, 0);
            }
        __builtin_amdgcn_s_setprio(0);

        __syncthreads();
        buf ^= 1;
    }

    // ---- in-block combine of the two key-splits (O^T layout) ----
    // o[dt][r] = O^T[d=dt*16+lg*4+r][q=li]; (mrun,lrun) per lane (q=li),
    // uniform across the lg quartet after the shfl reduces.
    float* cmb = (float*)&KVB[0][0][0];   // 4 waves x [16 q][64 d] f32 = 16KB
    float* mlc = (float*)&PsB[0][0];      // 64 rows x 2 floats
    if (g2 == 1) {
        float* dst = cmb + wq * 1024;
#pragma unroll
        for (int dt = 0; dt < 4; ++dt)
            *(f32x4*)(dst + li * 64 + dt * 16 + lg * 4) = o[dt];
        if (lg == 0) {
            float2 ml; ml.x = mrun; ml.y = lrun;
            *(float2*)(mlc + (wq * 16 + li) * 2) = ml;
        }
    }
    __syncthreads();
    if (g2 == 0) {
        float2 ml1 = *(const float2*)(mlc + (wq * 16 + li) * 2);
        float m = fmaxf(mrun, ml1.x);
        float w0 = __expf(mrun - m), w1 = __expf(ml1.x - m);
        float denom = 1.f / (lrun * w0 + ml1.y * w1);
        w0 *= denom; w1 *= denom;
        const float* src = cmb + wq * 1024;
        u16* orow = aob + (size_t)(b * N_ + m0 + li) * DM_ + h * DH_;
#pragma unroll
        for (int dt = 0; dt < 4; ++dt) {
            f32x4 p1 = *(const f32x4*)(src + li * 64 + dt * 16 + lg * 4);
            u16x4 ov;
#pragma unroll
            for (int r = 0; r < 4; ++r)
                ov[r] = f2bf(o[dt][r] * w0 + p1[r] * w1);
            *(u16x4*)(orow + dt * 16 + lg * 4) = ov;
        }
    }
}

// ---------------------------------------------------------------------------
extern "C" void kernel_launch(void* const* d_in, const int* in_sizes, int n_in,
                              void* d_out, int out_size, void* d_ws, size_t ws_size,
                              hipStream_t stream) {
    const float* x   = (const float*)d_in[0];
    const float* pde = (const float*)d_in[1];
    const int*   msk = (const int*)d_in[2];
    const float* Wq  = (const float*)d_in[3];
    const float* bq  = (const float*)d_in[4];
    const float* Wk  = (const float*)d_in[5];
    const float* bk  = (const float*)d_in[6];
    const float* Wv  = (const float*)d_in[7];
    const float* bv  = (const float*)d_in[8];
    const float* Wo  = (const float*)d_in[9];
    const float* bo  = (const float*)d_in[10];
    float* out = (float*)d_out;

    const size_t MAT = (size_t)B_ * N_ * DM_;   // 2M elements
    const size_t WSZ = (size_t)DM_ * DM_;
    u16* xb   = (u16*)d_ws;
    u16* q_bf = xb + MAT;
    u16* k_bf = q_bf + MAT;
    u16* vt   = k_bf + MAT;
    u16* aob  = vt + MAT;
    u16* wqb  = aob + MAT;
    u16* wkb  = wqb + WSZ;
    u16* wvb  = wkb + WSZ;
    u16* wob  = wvb + WSZ;
    float* rbs = (float*)(wob + WSZ);
    int* flags = (int*)(rbs + B_ * N_);

    cast_all<<<dim3(1024, 5), 256, 0, stream>>>(x, Wq, Wk, Wv, Wo,
                                                xb, wqb, wkb, wvb, wob);
    rb_kernel<<<(B_ * N_ + 255) / 256, 256, 0, stream>>>(pde, rbs);
    mask_scan<<<dim3(32, 32, 2), 256, 0, stream>>>(msk, flags);

    gemm_qkv<<<dim3(64, 24), 256, 0, stream>>>(xb, wqb, wkb, wvb,
                                               bq, bk, bv, q_bf, k_bf, vt);

    attn7<<<512, 512, 0, stream>>>(q_bf, k_bf, vt, rbs, msk, flags, aob);

    gemm_out<<<dim3(64, 8), 256, 0, stream>>>(aob, wob, bo, out);
}

// Round 10
// 76.893 us; speedup vs baseline: 6.5014x; 1.0422x over previous
//
#include <hip/hip_runtime.h>
#include <hip/hip_bf16.h>
#include <math.h>

#define B_ 2
#define N_ 2048
#define H_ 8
#define DH_ 64
#define DM_ 512
#define R_ 16
#define LAM_ 1.0f
#define SCALE_ 0.125f   // 1/sqrt(64)

typedef unsigned short u16;
typedef unsigned int u32;
typedef u16 u16x4 __attribute__((ext_vector_type(4)));
typedef u16 u16x8 __attribute__((ext_vector_type(8)));
typedef __bf16 bf16x8 __attribute__((ext_vector_type(8)));
typedef float f32x4 __attribute__((ext_vector_type(4)));

static __device__ __forceinline__ u16 f2bf(float f) {
    union { float f; unsigned u; } v; v.f = f;
    unsigned r = v.u + 0x7FFF + ((v.u >> 16) & 1);   // RNE
    return (u16)(r >> 16);
}

static __device__ __forceinline__ u32 pack_bf16(float lo, float hi) {
    float2 f2; f2.x = lo; f2.y = hi;
    __hip_bfloat162 h2 = __float22bfloat162_rn(f2);   // packed cvt, compiler-lowered
    u32 r;
    __builtin_memcpy(&r, &h2, 4);                     // bit_cast workaround
    return r;
}

static __device__ __forceinline__ void gl_lds16(const void* g, void* l) {
    __builtin_amdgcn_global_load_lds(
        (const __attribute__((address_space(1))) unsigned*)g,
        (__attribute__((address_space(3))) unsigned*)l, 16, 0, 0);
}

// ---------------------------------------------------------------------------
// bf16 casts: y=0 -> x (2M), y=1..4 -> Wq,Wk,Wv,Wo (256K each)
// ---------------------------------------------------------------------------
__global__ __launch_bounds__(256) void cast_all(
    const float* __restrict__ x, const float* __restrict__ wq,
    const float* __restrict__ wk, const float* __restrict__ wv,
    const float* __restrict__ wo, u16* __restrict__ xb, u16* __restrict__ wqb,
    u16* __restrict__ wkb, u16* __restrict__ wvb, u16* __restrict__ wob) {
    int y = blockIdx.y;
    const float* src; u16* dst; int n;
    switch (y) {
        case 0: src = x;  dst = xb;  n = 2097152; break;
        case 1: src = wq; dst = wqb; n = 262144;  break;
        case 2: src = wk; dst = wkb; n = 262144;  break;
        case 3: src = wv; dst = wvb; n = 262144;  break;
        default: src = wo; dst = wob; n = 262144; break;
    }
    int i = (blockIdx.x * 256 + threadIdx.x) * 8;
    if (i >= n) return;
    float4 a = *(const float4*)(src + i);
    float4 b = *(const float4*)(src + i + 4);
    u16x8 o;
    o[0] = f2bf(a.x); o[1] = f2bf(a.y); o[2] = f2bf(a.z); o[3] = f2bf(a.w);
    o[4] = f2bf(b.x); o[5] = f2bf(b.y); o[6] = f2bf(b.z); o[7] = f2bf(b.w);
    *(u16x8*)(dst + i) = o;
}

// ---------------------------------------------------------------------------
__global__ void rb_kernel(const float* __restrict__ pde, float* __restrict__ rbs) {
    int i = blockIdx.x * blockDim.x + threadIdx.x;
    if (i >= B_ * N_) return;
    const float4* p = (const float4*)(pde + (size_t)i * R_);
    float s = 0.f;
#pragma unroll
    for (int j = 0; j < 4; ++j) {
        float4 v = p[j];
        s += v.x * v.x + v.y * v.y + v.z * v.z + v.w * v.w;
    }
    rbs[i] = LAM_ * sqrtf(s);
}

// ---------------------------------------------------------------------------
__global__ __launch_bounds__(256) void mask_scan(const int* __restrict__ mask,
                                                 int* __restrict__ flags) {
    int kt = blockIdx.x, qt = blockIdx.y, b = blockIdx.z;
    __shared__ int red;
    if (threadIdx.x == 0) red = 0;
    __syncthreads();
    int any = 0;
    for (int c = threadIdx.x; c < 1024; c += 256) {
        int row = c >> 4, seg = c & 15;
        int4 m4 = *(const int4*)(mask + (size_t)b * N_ * N_ +
                                 (size_t)(qt * 64 + row) * N_ + kt * 64 + seg * 4);
        any |= (m4.x == 0) | (m4.y == 0) | (m4.z == 0) | (m4.w == 0);
    }
    if (__ballot(any)) {
        if ((threadIdx.x & 63) == 0) atomicOr(&red, 1);
    }
    __syncthreads();
    if (threadIdx.x == 0) flags[(b * 32 + qt) * 32 + kt] = red;
}

// ---------------------------------------------------------------------------
// bf16 MFMA GEMM core (m97 pattern): 64x64 tile, BK=64, 4 waves 32x32 each.
// ---------------------------------------------------------------------------
struct Acc { f32x4 v[2][2]; };

static __device__ __forceinline__ Acc gemm_core(const u16* __restrict__ A,
                                                const u16* __restrict__ W,
                                                int m0, int nn0, char* LDSB) {
    int t = threadIdx.x, l = t & 63, w = t >> 6;
    int lg = l >> 4, li = l & 15;
    int wr = w >> 1, wc = w & 1;
    Acc acc;
#pragma unroll
    for (int m = 0; m < 2; ++m)
#pragma unroll
        for (int n = 0; n < 2; ++n) acc.v[m][n] = (f32x4){0.f, 0.f, 0.f, 0.f};

    int srow_l = l >> 3;
    int colb = ((l & 7) * 16) ^ (srow_l << 4);   // pre-swizzled source col (bytes)

    for (int k0 = 0; k0 < DM_; k0 += 64) {
        __syncthreads();
#pragma unroll
        for (int i = 0; i < 2; ++i) {
            int c = w * 2 + i;
            int row = c * 8 + srow_l;
            gl_lds16(A + (size_t)(m0 + row) * DM_ + k0 + (colb >> 1),
                     LDSB + c * 1024);
            gl_lds16(W + (size_t)(nn0 + row) * DM_ + k0 + (colb >> 1),
                     LDSB + 8192 + c * 1024);
        }
        __syncthreads();
#pragma unroll
        for (int kk = 0; kk < 2; ++kk) {
            bf16x8 af[2], bfr[2];
#pragma unroll
            for (int m = 0; m < 2; ++m) {
                int r = wr * 32 + m * 16 + li;
                af[m] = *(const bf16x8*)(LDSB + r * 128 +
                                         ((kk * 64 + lg * 16) ^ ((r & 7) << 4)));
            }
#pragma unroll
            for (int n = 0; n < 2; ++n) {
                int r = wc * 32 + n * 16 + li;
                bfr[n] = *(const bf16x8*)(LDSB + 8192 + r * 128 +
                                          ((kk * 64 + lg * 16) ^ ((r & 7) << 4)));
            }
#pragma unroll
            for (int m = 0; m < 2; ++m)
#pragma unroll
                for (int n = 0; n < 2; ++n)
                    acc.v[m][n] = __builtin_amdgcn_mfma_f32_16x16x32_bf16(
                        af[m], bfr[n], acc.v[m][n], 0, 0, 0);
        }
    }
    return acc;
}

// ---------------------------------------------------------------------------
// Fused QKV GEMM. grid (64, 24): y>>3 = 0:Q 1:K 2:V
// ---------------------------------------------------------------------------
__global__ __launch_bounds__(256) void gemm_qkv(
    const u16* __restrict__ xb, const u16* __restrict__ wqb,
    const u16* __restrict__ wkb, const u16* __restrict__ wvb,
    const float* __restrict__ bq, const float* __restrict__ bk,
    const float* __restrict__ bv, u16* __restrict__ q_bf,
    u16* __restrict__ k_bf, u16* __restrict__ vt) {
    __shared__ char LDSB[24576];
    int y = blockIdx.y;
    int which = y >> 3;
    int nn0 = (y & 7) * 64;
    const u16* W = which == 0 ? wqb : which == 1 ? wkb : wvb;
    const float* bias = which == 0 ? bq : which == 1 ? bk : bv;
    int m0 = blockIdx.x * 64;
    Acc acc = gemm_core(xb, W, m0, nn0, LDSB);

    int t = threadIdx.x, l = t & 63, w = t >> 6;
    int lg = l >> 4, li = l & 15;
    int wr = w >> 1, wc = w & 1;
    float scale = which == 0 ? SCALE_ : 1.0f;
#pragma unroll
    for (int n = 0; n < 2; ++n) {
        int col = nn0 + wc * 32 + n * 16 + li;
        float bv_ = bias[col];
        if (which < 2) {
            u16* dst = which == 0 ? q_bf : k_bf;
#pragma unroll
            for (int m = 0; m < 2; ++m)
#pragma unroll
                for (int r = 0; r < 4; ++r) {
                    int row = m0 + wr * 32 + m * 16 + lg * 4 + r;
                    dst[(size_t)row * DM_ + col] =
                        f2bf((acc.v[m][n][r] + bv_) * scale);
                }
        } else {
            int h = col >> 6, d = col & 63;
#pragma unroll
            for (int m = 0; m < 2; ++m) {
                int row = m0 + wr * 32 + m * 16 + lg * 4;
                int b = row >> 11, nb = row & (N_ - 1);
                u16x4 o;
#pragma unroll
                for (int r = 0; r < 4; ++r) o[r] = f2bf(acc.v[m][n][r] + bv_);
                *(u16x4*)(vt + ((size_t)((b * 8 + h) * 64 + d)) * N_ + nb) = o;
            }
        }
    }
}

// ---------------------------------------------------------------------------
__global__ __launch_bounds__(256) void gemm_out(
    const u16* __restrict__ aob, const u16* __restrict__ wob,
    const float* __restrict__ bo, float* __restrict__ out) {
    __shared__ char LDSB[24576];
    int nn0 = blockIdx.y * 64;
    int m0 = blockIdx.x * 64;
    Acc acc = gemm_core(aob, wob, m0, nn0, LDSB);

    int t = threadIdx.x, l = t & 63, w = t >> 6;
    int lg = l >> 4, li = l & 15;
    int wr = w >> 1, wc = w & 1;
#pragma unroll
    for (int n = 0; n < 2; ++n) {
        int col = nn0 + wc * 32 + n * 16 + li;
        float bv_ = bo[col];
#pragma unroll
        for (int m = 0; m < 2; ++m)
#pragma unroll
            for (int r = 0; r < 4; ++r) {
                int row = m0 + wr * 32 + m * 16 + lg * 4 + r;
                out[(size_t)row * DM_ + col] = acc.v[m][n][r] + bv_;
            }
    }
}

// ---------------------------------------------------------------------------
// attn8: swapped-operand flash attention, in-block K-split x2 (R7-proven)
// + packed P via __float22bfloat162_rn (compiler-lowered cvt_pk)
// + conflict-free P layout [s*4+lgd][li*16+h*8] (slot == PV B-fragment)
// + defer-max (T13).
// ---------------------------------------------------------------------------
__global__ __launch_bounds__(512) void attn8(
    const u16* __restrict__ qb, const u16* __restrict__ kb,
    const u16* __restrict__ vtb, const float* __restrict__ rbs,
    const int* __restrict__ mask, const int* __restrict__ flags,
    u16* __restrict__ aob) {
    __shared__ char KVB[2][2][16384];   // [group][buf][0..8191 K | 8192.. V^T]
    __shared__ char PsB[8][2048];       // per wave: [8 slots][16 li][16B]

    int t = threadIdx.x, l = t & 63, w = t >> 6;   // w 0..7
    int g2 = w >> 2, wq = w & 3;
    int raw = blockIdx.x;
    int sid = (raw & 7) * 64 + (raw >> 3);   // XCD-contiguous (512 % 8 == 0)
    int bh = sid >> 5, qg = sid & 31;
    int b = bh >> 3, h = bh & 7;
    int m0 = qg * 64 + wq * 16;              // this wave's 16 q-rows
    int lg = l >> 4, li = l & 15;
    int k0base = g2 * 1024;

    int srl = l >> 3;
    int colb = ((l & 7) * 16) ^ (srl << 4);  // pre-swizzled source col (bytes)

    // Q fragments (B-operand): lane holds Q[qrow=li][d=s*32+lg*8+j]
    bf16x8 qa[2];
    {
        const u16* qrow = qb + (size_t)(b * N_ + m0 + li) * DM_ + h * DH_;
        qa[0] = __builtin_bit_cast(bf16x8, *(const u16x8*)(qrow + lg * 8));
        qa[1] = __builtin_bit_cast(bf16x8, *(const u16x8*)(qrow + 32 + lg * 8));
    }

    f32x4 o[4];   // o[dt][r] = O^T[d=dt*16+lg*4+r][q=li]  (unnormalized)
#pragma unroll
    for (int dt = 0; dt < 4; ++dt) o[dt] = (f32x4){0.f, 0.f, 0.f, 0.f};
    float mrun = -INFINITY, lrun = 0.f;

    auto STAGE = [&](int bufi, int k0s) {
        char* base = &KVB[g2][bufi][0];
#pragma unroll
        for (int c = 0; c < 2; ++c) {
            int chunk = wq * 2 + c;
            int row = chunk * 8 + srl;
            gl_lds16(kb + (size_t)(b * N_ + k0s + row) * DM_ + h * DH_ + (colb >> 1),
                     base + chunk * 1024);
            gl_lds16(vtb + ((size_t)(bh * DH_ + row)) * N_ + k0s + (colb >> 1),
                     base + 8192 + chunk * 1024);
        }
    };

    STAGE(0, k0base);
    __syncthreads();

    // P write slot base per lane (depends only on lg, li):
    //   slot(kt) = (kt>>1)*4 + (kt&1)*2 + (lg>>1); half = lg&1
    char* pwbase = &PsB[w][0] + li * 16 + ((lg & 1) << 3);
    int slot_lohi = (lg >> 1);               // + (kt&1)*2 + (kt>>1)*4

    int buf = 0;
    for (int tt = 0; tt < 16; ++tt) {
        int k0 = k0base + tt * 64;
        if (tt < 15) STAGE(buf ^ 1, k0 + 64);   // prefetch next tile

        const char* Kb = &KVB[g2][buf][0];
        const char* Vb = &KVB[g2][buf][8192];
        int flag = flags[(b * 32 + qg) * 32 + (k0 >> 6)];

        // ---- S^T = K.Q^T : st[kt][r] = S[key=kt*16+lg*4+r][q=li] ----
        f32x4 st[4];
        __builtin_amdgcn_s_setprio(1);
#pragma unroll
        for (int kt = 0; kt < 4; ++kt) {
            st[kt] = (f32x4){0.f, 0.f, 0.f, 0.f};
#pragma unroll
            for (int s = 0; s < 2; ++s) {
                int key = kt * 16 + li;
                bf16x8 kf = *(const bf16x8*)(Kb + key * 128 +
                                             ((s * 64 + lg * 16) ^ ((key & 7) << 4)));
                st[kt] = __builtin_amdgcn_mfma_f32_16x16x32_bf16(kf, qa[s], st[kt],
                                                                 0, 0, 0);
            }
        }
        __builtin_amdgcn_s_setprio(0);

        // ---- bias (keys consecutive in-lane -> float4 loads) ----
#pragma unroll
        for (int kt = 0; kt < 4; ++kt) {
            float4 rb4 = *(const float4*)(rbs + b * N_ + k0 + kt * 16 + lg * 4);
            st[kt][0] -= rb4.x; st[kt][1] -= rb4.y;
            st[kt][2] -= rb4.z; st[kt][3] -= rb4.w;
        }
        if (flag) {
#pragma unroll
            for (int kt = 0; kt < 4; ++kt)
#pragma unroll
                for (int r = 0; r < 4; ++r) {
                    int rowg = m0 + li;
                    int keyg = k0 + kt * 16 + lg * 4 + r;
                    if (mask[(size_t)b * N_ * N_ + (size_t)rowg * N_ + keyg] == 0)
                        st[kt][r] = -INFINITY;
                }
        }

        // ---- per-lane row max (in-lane tree + shfl over the lg quartet) ----
        float m0_ = fmaxf(fmaxf(st[0][0], st[0][1]), fmaxf(st[0][2], st[0][3]));
        float m1_ = fmaxf(fmaxf(st[1][0], st[1][1]), fmaxf(st[1][2], st[1][3]));
        float m2_ = fmaxf(fmaxf(st[2][0], st[2][1]), fmaxf(st[2][2], st[2][3]));
        float m3_ = fmaxf(fmaxf(st[3][0], st[3][1]), fmaxf(st[3][2], st[3][3]));
        float pmax = fmaxf(fmaxf(m0_, m1_), fmaxf(m2_, m3_));
        pmax = fmaxf(pmax, __shfl_xor(pmax, 16));
        pmax = fmaxf(pmax, __shfl_xor(pmax, 32));

        // ---- defer-max (T13): skip rescale while growth <= 8 ----
        if (!__all(pmax - mrun <= 8.0f)) {
            float mnew = fmaxf(fmaxf(mrun, pmax), -3.0e38f);
            float corr = __expf(mrun - mnew);
            mrun = mnew;
            lrun *= corr;
#pragma unroll
            for (int dt = 0; dt < 4; ++dt)
#pragma unroll
                for (int r = 0; r < 4; ++r) o[dt][r] *= corr;
        }

        // ---- P = exp(S - m), packed cvt, conflict-free slot write ----
        float ps[8];
#pragma unroll
        for (int kt = 0; kt < 4; ++kt) {
            float p0 = __expf(st[kt][0] - mrun);
            float p1 = __expf(st[kt][1] - mrun);
            float p2 = __expf(st[kt][2] - mrun);
            float p3 = __expf(st[kt][3] - mrun);
            ps[kt * 2 + 0] = p0 + p1;
            ps[kt * 2 + 1] = p2 + p3;
            uint2 pkw;
            pkw.x = pack_bf16(p0, p1);
            pkw.y = pack_bf16(p2, p3);
            int slot = (kt >> 1) * 4 + (kt & 1) * 2 + slot_lohi;
            *(uint2*)(pwbase + (slot << 8)) = pkw;
        }
        float psum = ((ps[0] + ps[1]) + (ps[2] + ps[3])) +
                     ((ps[4] + ps[5]) + (ps[6] + ps[7]));
        psum += __shfl_xor(psum, 16);
        psum += __shfl_xor(psum, 32);
        lrun += psum;

        // ---- O^T += V.P^T (pf read: 16 consecutive 16B per slot-row) ----
        bf16x8 pf[2];
#pragma unroll
        for (int s = 0; s < 2; ++s)
            pf[s] = *(const bf16x8*)(&PsB[w][0] + ((s * 4 + lg) << 8) + li * 16);
        __builtin_amdgcn_s_setprio(1);
#pragma unroll
        for (int dt = 0; dt < 4; ++dt)
#pragma unroll
            for (int s = 0; s < 2; ++s) {
                int d = dt * 16 + li;
                bf16x8 vf = *(const bf16x8*)(Vb + d * 128 +
                                             ((s * 64 + lg * 16) ^ ((d & 7) << 4)));
                o[dt] = __builtin_amdgcn_mfma_f32_16x16x32_bf16(vf, pf[s], o[dt],
                                                                0, 0, 0);
            }
        __builtin_amdgcn_s_setprio(0);

        __syncthreads();
        buf ^= 1;
    }

    // ---- in-block combine of the two key-splits (O^T layout) ----
    float* cmb = (float*)&KVB[0][0][0];   // 4 waves x [16 q][64 d] f32 = 16KB
    float* mlc = (float*)&PsB[0][0];      // 64 rows x 2 floats
    if (g2 == 1) {
        float* dst = cmb + wq * 1024;
#pragma unroll
        for (int dt = 0; dt < 4; ++dt)
            *(f32x4*)(dst + li * 64 + dt * 16 + lg * 4) = o[dt];
        if (lg == 0) {
            float2 ml; ml.x = mrun; ml.y = lrun;
            *(float2*)(mlc + (wq * 16 + li) * 2) = ml;
        }
    }
    __syncthreads();
    if (g2 == 0) {
        float2 ml1 = *(const float2*)(mlc + (wq * 16 + li) * 2);
        float m = fmaxf(mrun, ml1.x);
        float w0 = __expf(mrun - m), w1 = __expf(ml1.x - m);
        float denom = 1.f / (lrun * w0 + ml1.y * w1);
        w0 *= denom; w1 *= denom;
        const float* src = cmb + wq * 1024;
        u16* orow = aob + (size_t)(b * N_ + m0 + li) * DM_ + h * DH_;
#pragma unroll
        for (int dt = 0; dt < 4; ++dt) {
            f32x4 p1 = *(const f32x4*)(src + li * 64 + dt * 16 + lg * 4);
            u16x4 ov;
#pragma unroll
            for (int r = 0; r < 4; ++r)
                ov[r] = f2bf(o[dt][r] * w0 + p1[r] * w1);
            *(u16x4*)(orow + dt * 16 + lg * 4) = ov;
        }
    }
}

// ---------------------------------------------------------------------------
extern "C" void kernel_launch(void* const* d_in, const int* in_sizes, int n_in,
                              void* d_out, int out_size, void* d_ws, size_t ws_size,
                              hipStream_t stream) {
    const float* x   = (const float*)d_in[0];
    const float* pde = (const float*)d_in[1];
    const int*   msk = (const int*)d_in[2];
    const float* Wq  = (const float*)d_in[3];
    const float* bq  = (const float*)d_in[4];
    const float* Wk  = (const float*)d_in[5];
    const float* bk  = (const float*)d_in[6];
    const float* Wv  = (const float*)d_in[7];
    const float* bv  = (const float*)d_in[8];
    const float* Wo  = (const float*)d_in[9];
    const float* bo  = (const float*)d_in[10];
    float* out = (float*)d_out;

    const size_t MAT = (size_t)B_ * N_ * DM_;   // 2M elements
    const size_t WSZ = (size_t)DM_ * DM_;
    u16* xb   = (u16*)d_ws;
    u16* q_bf = xb + MAT;
    u16* k_bf = q_bf + MAT;
    u16* vt   = k_bf + MAT;
    u16* aob  = vt + MAT;
    u16* wqb  = aob + MAT;
    u16* wkb  = wqb + WSZ;
    u16* wvb  = wkb + WSZ;
    u16* wob  = wvb + WSZ;
    float* rbs = (float*)(wob + WSZ);
    int* flags = (int*)(rbs + B_ * N_);

    cast_all<<<dim3(1024, 5), 256, 0, stream>>>(x, Wq, Wk, Wv, Wo,
                                                xb, wqb, wkb, wvb, wob);
    rb_kernel<<<(B_ * N_ + 255) / 256, 256, 0, stream>>>(pde, rbs);
    mask_scan<<<dim3(32, 32, 2), 256, 0, stream>>>(msk, flags);

    gemm_qkv<<<dim3(64, 24), 256, 0, stream>>>(xb, wqb, wkb, wvb,
                                               bq, bk, bv, q_bf, k_bf, vt);

    attn8<<<512, 512, 0, stream>>>(q_bf, k_bf, vt, rbs, msk, flags, aob);

    gemm_out<<<dim3(64, 8), 256, 0, stream>>>(aob, wob, bo, out);
}